// Round 1
// baseline (633.385 us; speedup 1.0000x reference)
//
#include <hip/hip_runtime.h>
#include <hip/hip_bf16.h>
#include <math.h>

// Problem constants (from reference)
constexpr int Rc  = 3;
constexpr int Nc  = 100000;
constexpr int Fc  = 256;     // feature dim
constexpr int Hc  = 128;     // hidden dim
constexpr int N0c = 16384;
constexpr int S1c = 16384;
constexpr int D1c = 4096;
constexpr int S2c = 4096;
constexpr int D2c = 512;

typedef __bf16 bf16x8 __attribute__((ext_vector_type(8)));
typedef float  f32x4  __attribute__((ext_vector_type(4)));

// ---------------------------------------------------------------------------
// K1: gather features rows via src_nodes[dstsrc2src1] and write TRANSPOSED
//     bf16 panel xgT[r][f][s]  (f=0..255, s=0..16383) so GEMM1's B operand is
//     K-contiguous.
// ---------------------------------------------------------------------------
__global__ __launch_bounds__(256, 1)
void k1_gather_t(const float* __restrict__ feat, const int* __restrict__ srcn,
                 const int* __restrict__ d2s1, __bf16* __restrict__ xgT) {
  const int rel = blockIdx.y;
  const int s0  = blockIdx.x * 64;
  const int t   = threadIdx.x;
  __shared__ __bf16 sm[64][264];   // 33 KB, padded rows (stride 528B, 16B-mult)

  // load phase: 64 nodes x 256 feats; 4 threads/node, 64 floats each
  const int nl = t >> 2, q = t & 3, f0 = q * 64;
  const int s  = s0 + nl;
  const int node = srcn[rel * N0c + d2s1[rel * S1c + s]];
  const float4* fr = (const float4*)(feat + (size_t)node * Fc + f0);
#pragma unroll
  for (int j = 0; j < 8; j++) {
    float4 v0 = fr[2 * j], v1 = fr[2 * j + 1];
    bf16x8 b;
    b[0] = (__bf16)v0.x; b[1] = (__bf16)v0.y; b[2] = (__bf16)v0.z; b[3] = (__bf16)v0.w;
    b[4] = (__bf16)v1.x; b[5] = (__bf16)v1.y; b[6] = (__bf16)v1.z; b[7] = (__bf16)v1.w;
    *(bf16x8*)&sm[nl][f0 + 8 * j] = b;
  }
  __syncthreads();
  // store phase: thread t owns feature row f=t, writes 64 contiguous s values
  __bf16* orow = xgT + ((size_t)rel * Fc + t) * S1c + s0;
#pragma unroll
  for (int m = 0; m < 8; m++) {
    bf16x8 v;
#pragma unroll
    for (int u = 0; u < 8; u++) v[u] = sm[m * 8 + u][t];
    *(bf16x8*)&orow[m * 8] = v;
  }
}

// ---------------------------------------------------------------------------
// K2: GEMM1  aggP[kh][r] += dif1[r][m][k] * xg[k][n]   (bf16 MFMA, fp32 acc)
//     tile 64x256, BK=64, K split in 2 halves (kh) for occupancy.
// ---------------------------------------------------------------------------
__global__ __launch_bounds__(256, 1)
void k2_gemm1(const float* __restrict__ dif1, const __bf16* __restrict__ xgT,
              float* __restrict__ aggP) {
  const int rel = blockIdx.z, kh = blockIdx.y;
  const int m0  = blockIdx.x * 64;
  const int t = threadIdx.x, lane = t & 63, w = t >> 6;

  const float*  Ag = dif1 + ((size_t)rel * D1c + m0) * S1c + (size_t)kh * 8192;
  const __bf16* Bg = xgT + (size_t)rel * Fc * S1c + (size_t)kh * 8192;
  float*        Cg = aggP + (((size_t)kh * Rc + rel) * D1c + m0) * Fc;

  __shared__ __bf16 Asm[64 * 64];    // [row][k] swizzled, 8 KB
  __shared__ __bf16 Bsm[256 * 64];   // [n][k]   swizzled, 32 KB

  f32x4 acc[4][4] = {};

  const int arow = t >> 2, ak0 = (t & 3) * 16;     // A stage: 4 thr/row, 16 floats
  const float* aptr = Ag + (size_t)arow * S1c + ak0;
  const int ac0 = ak0 >> 3;                         // first of 2 chunks
  const int bn0 = t >> 3, bch = t & 7;              // B stage: 8 thr/row

#pragma unroll 1
  for (int kk = 0; kk < 8192; kk += 64) {
    __syncthreads();
    // ---- stage A (fp32 -> bf16) ----
    float4 a0 = *(const float4*)(aptr + kk);
    float4 a1 = *(const float4*)(aptr + kk + 4);
    float4 a2 = *(const float4*)(aptr + kk + 8);
    float4 a3 = *(const float4*)(aptr + kk + 12);
    bf16x8 c0, c1;
    c0[0]=(__bf16)a0.x; c0[1]=(__bf16)a0.y; c0[2]=(__bf16)a0.z; c0[3]=(__bf16)a0.w;
    c0[4]=(__bf16)a1.x; c0[5]=(__bf16)a1.y; c0[6]=(__bf16)a1.z; c0[7]=(__bf16)a1.w;
    c1[0]=(__bf16)a2.x; c1[1]=(__bf16)a2.y; c1[2]=(__bf16)a2.z; c1[3]=(__bf16)a2.w;
    c1[4]=(__bf16)a3.x; c1[5]=(__bf16)a3.y; c1[6]=(__bf16)a3.z; c1[7]=(__bf16)a3.w;
    *(bf16x8*)&Asm[arow * 64 + ((ac0    ) ^ (arow & 7)) * 8] = c0;
    *(bf16x8*)&Asm[arow * 64 + ((ac0 + 1) ^ (arow & 7)) * 8] = c1;
    // ---- stage B (bf16 copy, swizzled) ----
#pragma unroll
    for (int i = 0; i < 8; i++) {
      int n = bn0 + i * 32;
      bf16x8 v = *(const bf16x8*)(Bg + (size_t)n * S1c + kk + bch * 8);
      *(bf16x8*)&Bsm[n * 64 + (bch ^ (n & 7)) * 8] = v;
    }
    __syncthreads();
    // ---- compute ----
#pragma unroll
    for (int ks = 0; ks < 2; ks++) {
      bf16x8 af[4], bf[4];
      const int ch = ks * 4 + (lane >> 4);
#pragma unroll
      for (int mi = 0; mi < 4; mi++) {
        int row = mi * 16 + (lane & 15);
        af[mi] = *(const bf16x8*)&Asm[row * 64 + (ch ^ (row & 7)) * 8];
      }
#pragma unroll
      for (int ni = 0; ni < 4; ni++) {
        int n = w * 64 + ni * 16 + (lane & 15);
        bf[ni] = *(const bf16x8*)&Bsm[n * 64 + (ch ^ (n & 7)) * 8];
      }
#pragma unroll
      for (int mi = 0; mi < 4; mi++)
#pragma unroll
        for (int ni = 0; ni < 4; ni++)
          acc[mi][ni] = __builtin_amdgcn_mfma_f32_16x16x32_bf16(af[mi], bf[ni], acc[mi][ni], 0, 0, 0);
    }
  }
  // ---- epilogue ----
#pragma unroll
  for (int mi = 0; mi < 4; mi++)
#pragma unroll
    for (int ni = 0; ni < 4; ni++) {
      int col = w * 64 + ni * 16 + (lane & 15);
#pragma unroll
      for (int j = 0; j < 4; j++) {
        int row = mi * 16 + (lane >> 4) * 4 + j;
        Cg[(size_t)row * Fc + col] = acc[mi][ni][j];
      }
    }
}

// ---------------------------------------------------------------------------
// K3: h1 = [agg | x[d2d1]] @ w1 ; raw score1 = h1 . att_vec[0:128]
//     8 rows per block, 128 threads (thread = hidden unit)
// ---------------------------------------------------------------------------
__global__ __launch_bounds__(128, 1)
void k3_h1(const float* __restrict__ aggP, const float* __restrict__ feat,
           const int* __restrict__ srcn, const int* __restrict__ d2d1,
           const float* __restrict__ wmat, const float* __restrict__ attv,
           float* __restrict__ h1, float* __restrict__ score1) {
  const int rel = blockIdx.y, d0 = blockIdx.x * 8, t = threadIdx.x;
  __shared__ float rows[8][512];
  const float* A0 = aggP + (size_t)rel * D1c * Fc;
  const float* A1 = aggP + (size_t)(Rc + rel) * D1c * Fc;
#pragma unroll
  for (int i = 0; i < 8; i++) {
    const int d = d0 + i;
    if (t < 64) {
      const int f = t * 4;
      float4 v0 = *(const float4*)(A0 + (size_t)d * Fc + f);
      float4 v1 = *(const float4*)(A1 + (size_t)d * Fc + f);
      float4 v; v.x = v0.x + v1.x; v.y = v0.y + v1.y; v.z = v0.z + v1.z; v.w = v0.w + v1.w;
      *(float4*)&rows[i][f] = v;
    } else {
      const int f = (t - 64) * 4;
      const int node = srcn[rel * N0c + d2d1[rel * D1c + d]];
      float4 v = *(const float4*)(feat + (size_t)node * Fc + f);
      *(float4*)&rows[i][256 + f] = v;
    }
  }
  __syncthreads();
  float acc[8] = {0, 0, 0, 0, 0, 0, 0, 0};
  for (int k = 0; k < 512; k += 4) {
    const float w0 = wmat[(k + 0) * Hc + t];
    const float w1v = wmat[(k + 1) * Hc + t];
    const float w2v = wmat[(k + 2) * Hc + t];
    const float w3v = wmat[(k + 3) * Hc + t];
#pragma unroll
    for (int i = 0; i < 8; i++) {
      float4 rv = *(const float4*)&rows[i][k];
      acc[i] += rv.x * w0 + rv.y * w1v + rv.z * w2v + rv.w * w3v;
    }
  }
#pragma unroll
  for (int i = 0; i < 8; i++)
    h1[((size_t)rel * D1c + d0 + i) * Hc + t] = acc[i];
  // score = sum_t acc*av[t]  (rel-vector term is softmax-invariant, dropped)
  const float avt = attv[t];
  __shared__ float sred[2][8];
#pragma unroll
  for (int i = 0; i < 8; i++) {
    float p = acc[i] * avt;
    p += __shfl_down(p, 32); p += __shfl_down(p, 16); p += __shfl_down(p, 8);
    p += __shfl_down(p, 4);  p += __shfl_down(p, 2);  p += __shfl_down(p, 1);
    if ((t & 63) == 0) sred[t >> 6][i] = p;
  }
  __syncthreads();
  if (t < 8) score1[rel * D1c + d0 + t] = sred[0][t] + sred[1][t];
}

// ---------------------------------------------------------------------------
// K4: softmax over 4096 scores per relation (in place -> attention weights)
// ---------------------------------------------------------------------------
__global__ __launch_bounds__(1024, 1)
void k4_softmax1(float* __restrict__ score1) {
  const int rel = blockIdx.x, t = threadIdx.x;
  float* s = score1 + rel * D1c;
  float v[4], m = -INFINITY;
#pragma unroll
  for (int j = 0; j < 4; j++) { v[j] = s[t + j * 1024]; m = fmaxf(m, v[j]); }
  __shared__ float red[1024];
  red[t] = m; __syncthreads();
  for (int off = 512; off > 0; off >>= 1) {
    if (t < off) red[t] = fmaxf(red[t], red[t + off]);
    __syncthreads();
  }
  const float M = red[0];
  __syncthreads();
  float e[4], sum = 0.f;
#pragma unroll
  for (int j = 0; j < 4; j++) { e[j] = expf(v[j] - M); sum += e[j]; }
  red[t] = sum; __syncthreads();
  for (int off = 512; off > 0; off >>= 1) {
    if (t < off) red[t] += red[t + off];
    __syncthreads();
  }
  const float inv = 1.0f / red[0];
#pragma unroll
  for (int j = 0; j < 4; j++) s[t + j * 1024] = e[j] * inv;
}

// ---------------------------------------------------------------------------
// K5: x1 = h1 * att1 (row-broadcast scale), float4 elementwise
// ---------------------------------------------------------------------------
__global__ __launch_bounds__(256, 1)
void k5_scale1(const float* __restrict__ h1, const float* __restrict__ att1,
               float* __restrict__ x1) {
  const size_t i = ((size_t)blockIdx.x * 256 + threadIdx.x) * 4;
  float4 h = *(const float4*)(h1 + i);
  const float a = att1[i >> 7];
  float4 o; o.x = h.x * a; o.y = h.y * a; o.z = h.z * a; o.w = h.w * a;
  *(float4*)(x1 + i) = o;
}

// ---------------------------------------------------------------------------
// K6: agg2[r][d][h] = sum_s dif2[r][d][s] * x1[r][d2s2[r][s]][h]
//     16 rows/block, 256 threads = 2 groups of 128 splitting s
// ---------------------------------------------------------------------------
__global__ __launch_bounds__(256, 1)
void k6_gemm2(const float* __restrict__ dif2, const int* __restrict__ d2s2,
              const float* __restrict__ x1, float* __restrict__ agg2) {
  const int rel = blockIdx.y, d0 = blockIdx.x * 16;
  const int t = threadIdx.x, th = t & 127, g = t >> 7;
  __shared__ float dt[16][256];
  __shared__ int   sidx[256];
  __shared__ float red[16][128];
  float acc[16] = {};
  const float* x1r = x1 + (size_t)rel * D1c * Hc;
#pragma unroll 1
  for (int c = 0; c < 16; c++) {
    const int sb = c * 256;
    __syncthreads();
    {
      const int i = t >> 4, ko = (t & 15) * 16;
      const float* dp = dif2 + ((size_t)rel * D2c + d0 + i) * S2c + sb + ko;
      float4 q0 = ((const float4*)dp)[0];
      float4 q1 = ((const float4*)dp)[1];
      float4 q2 = ((const float4*)dp)[2];
      float4 q3 = ((const float4*)dp)[3];
      *(float4*)&dt[i][ko]      = q0;
      *(float4*)&dt[i][ko + 4]  = q1;
      *(float4*)&dt[i][ko + 8]  = q2;
      *(float4*)&dt[i][ko + 12] = q3;
    }
    sidx[t] = d2s2[rel * S2c + sb + t];
    __syncthreads();
#pragma unroll 4
    for (int jj = 0; jj < 128; jj++) {
      const int j = g * 128 + jj;
      const int row = sidx[j];
      const float xv = x1r[(size_t)row * Hc + th];
#pragma unroll
      for (int i = 0; i < 16; i++) acc[i] += dt[i][j] * xv;
    }
  }
  if (g == 1) {
#pragma unroll
    for (int i = 0; i < 16; i++) red[i][th] = acc[i];
  }
  __syncthreads();
  if (g == 0) {
#pragma unroll
    for (int i = 0; i < 16; i++)
      agg2[((size_t)rel * D2c + d0 + i) * Hc + th] = acc[i] + red[i][th];
  }
}

// ---------------------------------------------------------------------------
// K7: h2 = [agg2 | x1[d2d2]] @ w2 ; raw score2
// ---------------------------------------------------------------------------
__global__ __launch_bounds__(128, 1)
void k7_h2(const float* __restrict__ agg2, const float* __restrict__ x1,
           const int* __restrict__ d2d2, const float* __restrict__ wmat,
           const float* __restrict__ attv, float* __restrict__ h2,
           float* __restrict__ score2) {
  const int rel = blockIdx.y, d0 = blockIdx.x * 8, t = threadIdx.x;
  __shared__ float rows[8][256];
#pragma unroll
  for (int i = 0; i < 8; i++) {
    const int d = d0 + i;
    if (t < 64) {
      const int f = t * 2;
      *(float2*)&rows[i][f] = *(const float2*)(agg2 + ((size_t)rel * D2c + d) * Hc + f);
    } else {
      const int f = (t - 64) * 2;
      const int rrow = d2d2[rel * D2c + d];
      *(float2*)&rows[i][128 + f] = *(const float2*)(x1 + ((size_t)rel * D1c + rrow) * Hc + f);
    }
  }
  __syncthreads();
  float acc[8] = {0, 0, 0, 0, 0, 0, 0, 0};
  for (int k = 0; k < 256; k += 4) {
    const float w0 = wmat[(k + 0) * Hc + t];
    const float w1v = wmat[(k + 1) * Hc + t];
    const float w2v = wmat[(k + 2) * Hc + t];
    const float w3v = wmat[(k + 3) * Hc + t];
#pragma unroll
    for (int i = 0; i < 8; i++) {
      float4 rv = *(const float4*)&rows[i][k];
      acc[i] += rv.x * w0 + rv.y * w1v + rv.z * w2v + rv.w * w3v;
    }
  }
#pragma unroll
  for (int i = 0; i < 8; i++)
    h2[((size_t)rel * D2c + d0 + i) * Hc + t] = acc[i];
  const float avt = attv[t];
  __shared__ float sred[2][8];
#pragma unroll
  for (int i = 0; i < 8; i++) {
    float p = acc[i] * avt;
    p += __shfl_down(p, 32); p += __shfl_down(p, 16); p += __shfl_down(p, 8);
    p += __shfl_down(p, 4);  p += __shfl_down(p, 2);  p += __shfl_down(p, 1);
    if ((t & 63) == 0) sred[t >> 6][i] = p;
  }
  __syncthreads();
  if (t < 8) score2[rel * D2c + d0 + t] = sred[0][t] + sred[1][t];
}

// ---------------------------------------------------------------------------
// K8: softmax over 512 scores per relation (in place)
// ---------------------------------------------------------------------------
__global__ __launch_bounds__(512, 1)
void k8_softmax2(float* __restrict__ score2) {
  const int rel = blockIdx.x, t = threadIdx.x;
  float* s = score2 + rel * D2c;
  const float v = s[t];
  __shared__ float red[512];
  red[t] = v; __syncthreads();
  for (int off = 256; off > 0; off >>= 1) {
    if (t < off) red[t] = fmaxf(red[t], red[t + off]);
    __syncthreads();
  }
  const float M = red[0];
  __syncthreads();
  const float e = expf(v - M);
  red[t] = e; __syncthreads();
  for (int off = 256; off > 0; off >>= 1) {
    if (t < off) red[t] += red[t + off];
    __syncthreads();
  }
  s[t] = e / red[0];
}

// ---------------------------------------------------------------------------
// K9: summed = sum_r h2*att2 ; l2-normalize row; logits = normed@cw; softmax2
// ---------------------------------------------------------------------------
__global__ __launch_bounds__(128, 1)
void k9_final(const float* __restrict__ h2, const float* __restrict__ att2,
              const float* __restrict__ cw, float* __restrict__ out) {
  const int d = blockIdx.x, t = threadIdx.x;
  float v = 0.f;
#pragma unroll
  for (int r = 0; r < Rc; r++)
    v += h2[((size_t)r * D2c + d) * Hc + t] * att2[r * D2c + d];
  float ss = v * v;
  ss += __shfl_down(ss, 32); ss += __shfl_down(ss, 16); ss += __shfl_down(ss, 8);
  ss += __shfl_down(ss, 4);  ss += __shfl_down(ss, 2);  ss += __shfl_down(ss, 1);
  __shared__ float sr[3][2];
  if ((t & 63) == 0) sr[0][t >> 6] = ss;
  __syncthreads();
  const float tot = sr[0][0] + sr[0][1];
  const float inv = rsqrtf(fmaxf(tot, 1e-12f));
  const float nv = v * inv;
  float p0 = nv * cw[t * 2], p1 = nv * cw[t * 2 + 1];
  p0 += __shfl_down(p0, 32); p0 += __shfl_down(p0, 16); p0 += __shfl_down(p0, 8);
  p0 += __shfl_down(p0, 4);  p0 += __shfl_down(p0, 2);  p0 += __shfl_down(p0, 1);
  p1 += __shfl_down(p1, 32); p1 += __shfl_down(p1, 16); p1 += __shfl_down(p1, 8);
  p1 += __shfl_down(p1, 4);  p1 += __shfl_down(p1, 2);  p1 += __shfl_down(p1, 1);
  if ((t & 63) == 0) { sr[1][t >> 6] = p0; sr[2][t >> 6] = p1; }
  __syncthreads();
  if (t == 0) {
    const float l0 = sr[1][0] + sr[1][1];
    const float l1 = sr[2][0] + sr[2][1];
    const float m = fmaxf(l0, l1);
    const float e0 = expf(l0 - m), e1 = expf(l1 - m);
    const float is = 1.0f / (e0 + e1);
    out[d * 2 + 0] = e0 * is;
    out[d * 2 + 1] = e1 * is;
  }
}

// ---------------------------------------------------------------------------
extern "C" void kernel_launch(void* const* d_in, const int* in_sizes, int n_in,
                              void* d_out, int out_size, void* d_ws, size_t ws_size,
                              hipStream_t stream) {
  (void)in_sizes; (void)n_in; (void)out_size; (void)ws_size;
  const float* feat = (const float*)d_in[0];
  const int*   srcn = (const int*)d_in[1];
  const int*   d2s1 = (const int*)d_in[2];
  const int*   d2d1 = (const int*)d_in[3];
  const float* dif1 = (const float*)d_in[4];
  const int*   d2s2 = (const int*)d_in[5];
  const int*   d2d2 = (const int*)d_in[6];
  const float* dif2 = (const float*)d_in[7];
  const float* w1   = (const float*)d_in[8];
  const float* w2   = (const float*)d_in[9];
  // d_in[10] relation_vectors: contributes a per-relation constant to the
  // attention score -> softmax-invariant -> unused.
  const float* attv = (const float*)d_in[11];
  const float* cw   = (const float*)d_in[12];
  float* out = (float*)d_out;

  char* p = (char*)d_ws;
  auto take = [&](size_t n) { char* r = p; p += (n + 255) & ~(size_t)255; return r; };
  __bf16* xgT   = (__bf16*)take((size_t)Rc * Fc * S1c * 2);        // 24 MB
  float*  aggP  = (float*) take((size_t)2 * Rc * D1c * Fc * 4);    // 24 MB (k-split partials)
  float*  h1    = (float*) take((size_t)Rc * D1c * Hc * 4);        // 6 MB
  float*  score1= (float*) take((size_t)Rc * D1c * 4);
  float*  x1    = (float*) take((size_t)Rc * D1c * Hc * 4);        // 6 MB
  float*  agg2  = (float*) take((size_t)Rc * D2c * Hc * 4);
  float*  h2    = (float*) take((size_t)Rc * D2c * Hc * 4);
  float*  score2= (float*) take((size_t)Rc * D2c * 4);

  k1_gather_t<<<dim3(S1c / 64, Rc), 256, 0, stream>>>(feat, srcn, d2s1, xgT);
  k2_gemm1<<<dim3(D1c / 64, 2, Rc), 256, 0, stream>>>(dif1, xgT, aggP);
  k3_h1<<<dim3(D1c / 8, Rc), 128, 0, stream>>>(aggP, feat, srcn, d2d1, w1, attv, h1, score1);
  k4_softmax1<<<Rc, 1024, 0, stream>>>(score1);
  k5_scale1<<<(Rc * D1c * Hc) / (256 * 4), 256, 0, stream>>>(h1, score1, x1);
  k6_gemm2<<<dim3(D2c / 16, Rc), 256, 0, stream>>>(dif2, d2s2, x1, agg2);
  k7_h2<<<dim3(D2c / 8, Rc), 128, 0, stream>>>(agg2, x1, d2d2, w2, attv, h2, score2);
  k8_softmax2<<<Rc, 512, 0, stream>>>(score2);
  k9_final<<<D2c, 128, 0, stream>>>(h2, score2, cw, out);
}

// Round 2
// 431.217 us; speedup vs baseline: 1.4688x; 1.4688x over previous
//
#include <hip/hip_runtime.h>
#include <hip/hip_bf16.h>
#include <math.h>

// Problem constants (from reference)
constexpr int Rc  = 3;
constexpr int Fc  = 256;     // feature dim
constexpr int Hc  = 128;     // hidden dim
constexpr int N0c = 16384;
constexpr int S1c = 16384;
constexpr int D1c = 4096;
constexpr int S2c = 4096;
constexpr int D2c = 512;

typedef __bf16 bf16x8 __attribute__((ext_vector_type(8)));
typedef float  f32x4  __attribute__((ext_vector_type(4)));

__device__ __forceinline__ void glds16(const void* g, void* l) {
  __builtin_amdgcn_global_load_lds(
      (const __attribute__((address_space(1))) void*)g,
      (__attribute__((address_space(3))) void*)l, 16, 0, 0);
}

__device__ __forceinline__ bf16x8 cvt2(const float4 a, const float4 b) {
  bf16x8 c;
  c[0] = (__bf16)a.x; c[1] = (__bf16)a.y; c[2] = (__bf16)a.z; c[3] = (__bf16)a.w;
  c[4] = (__bf16)b.x; c[5] = (__bf16)b.y; c[6] = (__bf16)b.z; c[7] = (__bf16)b.w;
  return c;
}

// ---------------------------------------------------------------------------
// K1: gather feature rows via src_nodes[dstsrc2src1], convert to bf16, and
//     write TILE-PACKED PRE-SWIZZLED B panels: for each k-tile kb (64 s vals),
//     a contiguous 32KB tile laid out exactly as k2's LDS image:
//     tile[n][cs]*16B where data chunk ch (k = kb*64+ch*8+e) sits at
//     cs = ch ^ (n&7).  k2 then stages B with a linear global_load_lds copy.
// ---------------------------------------------------------------------------
__global__ __launch_bounds__(256, 2)
void k1_gather_t(const float* __restrict__ feat, const int* __restrict__ srcn,
                 const int* __restrict__ d2s1, __bf16* __restrict__ xgT) {
  const int rel = blockIdx.y;
  const int kb  = blockIdx.x;          // k-tile index (64 s values)
  const int t   = threadIdx.x;
  __shared__ __bf16 sm[64][264];       // [s_local][f], padded

  // load phase: 64 nodes x 256 feats; 4 threads/node, 64 floats each
  const int nl = t >> 2, q = t & 3, f0 = q * 64;
  const int s  = kb * 64 + nl;
  const int node = srcn[rel * N0c + d2s1[rel * S1c + s]];
  const float4* fr = (const float4*)(feat + (size_t)node * Fc + f0);
#pragma unroll
  for (int j = 0; j < 8; j++) {
    float4 v0 = fr[2 * j], v1 = fr[2 * j + 1];
    *(bf16x8*)&sm[nl][f0 + 8 * j] = cvt2(v0, v1);
  }
  __syncthreads();
  // pack phase: thread t owns B-row n=f=t; writes 128B contiguous (swizzled)
  const int f = t;
  __bf16* orow = xgT + ((size_t)(rel * (S1c >> 6) + kb) * 256 + f) * 64;
#pragma unroll
  for (int cs = 0; cs < 8; cs++) {
    const int ch = cs ^ (f & 7);
    bf16x8 v;
#pragma unroll
    for (int e = 0; e < 8; e++) v[e] = sm[ch * 8 + e][f];
    *(bf16x8*)&orow[cs * 8] = v;
  }
}

// ---------------------------------------------------------------------------
// K2: GEMM1  aggP[kh][r] = dif1[r][m][k-slice] * xg[k][n]  (bf16 MFMA)
//     tile 64x256, BK=64, K split KH ways (blockIdx.y).  HBM-bound on dif1.
//     A: reg-double-buffered (prefetch next tile across the barrier);
//     B: linear 32KB global_load_lds from the pre-swizzled packed panel.
//     Counted-vmcnt raw-barrier loop (T4): A prefetch never drained.
// ---------------------------------------------------------------------------
__global__ __launch_bounds__(256, 3)
void k2_gemm1(const float* __restrict__ dif1, const __bf16* __restrict__ xgT,
              float* __restrict__ aggP) {
  const int rel = blockIdx.z, kh = blockIdx.y, KH = gridDim.y;
  const int m0  = blockIdx.x * 64;
  const int t = threadIdx.x, lane = t & 63, w = t >> 6;
  const int KB = S1c / KH;             // K extent per block
  const int NT = KB >> 6;              // number of 64-wide k-tiles

  const float* Ag = dif1 + ((size_t)rel * D1c + m0) * S1c + (size_t)kh * KB;
  const char*  Bt = (const char*)xgT +
                    ((size_t)(rel * (S1c >> 6) + kh * NT)) * 32768;
  float* Cg = aggP + (((size_t)kh * Rc + rel) * D1c + m0) * Fc;

  __shared__ __bf16 Asm[64 * 64];      // 8 KB  [row][chunk^ (row&7)]
  __shared__ __bf16 Bsm[256 * 64];     // 32 KB linear image of packed tile

  f32x4 acc[4][4] = {};

  // A staging: 4 threads/row, 16 consecutive floats each
  const int arow = t >> 2, ak0 = (t & 3) * 16;
  const float* aptr = Ag + (size_t)arow * S1c + ak0;
  const int ac0 = ak0 >> 3;
  __bf16* asw0 = &Asm[arow * 64 + ((ac0    ) ^ (arow & 7)) * 8];
  __bf16* asw1 = &Asm[arow * 64 + ((ac0 + 1) ^ (arow & 7)) * 8];

  // B staging: per wave 8 x 1KB linear global_load_lds
  const char* bsrc = Bt + w * 8192 + lane * 16;
  char*       bdst = (char*)Bsm + w * 8192;    // wave-uniform (HW adds lane*16)

  float4 a0[4], a1[4];
#pragma unroll
  for (int j = 0; j < 4; j++) a0[j] = *(const float4*)(aptr + 4 * j);

  for (int tl = 0; tl < NT; ++tl) {
    // top barrier: my ds_reads of prev tile done (lgkm), then sync.
    // A-prefetch (vmcnt) intentionally NOT drained.
    asm volatile("s_waitcnt lgkmcnt(0)" ::: "memory");
    __builtin_amdgcn_s_barrier();
    __builtin_amdgcn_sched_barrier(0);

    // ---- issue B tile copy (global -> LDS direct) ----
    const char* bs = bsrc + (size_t)tl * 32768;
#pragma unroll
    for (int i = 0; i < 8; i++) glds16(bs + i * 1024, bdst + i * 1024);
    // ---- issue A prefetch for next tile ----
    if (tl + 1 < NT) {
      const float* ap = aptr + (tl + 1) * 64;
#pragma unroll
      for (int j = 0; j < 4; j++) a1[j] = *(const float4*)(ap + 4 * j);
    }
    // ---- convert current A regs -> LDS (compiler waits a0 with counted vmcnt) ----
    *(bf16x8*)asw0 = cvt2(a0[0], a0[1]);
    *(bf16x8*)asw1 = cvt2(a0[2], a0[3]);

    // mid barrier: B landed (allow 4 A-prefetch loads to stay in flight),
    // ds_writes visible, then sync.
    asm volatile("s_waitcnt vmcnt(4) lgkmcnt(0)" ::: "memory");
    __builtin_amdgcn_s_barrier();
    __builtin_amdgcn_sched_barrier(0);

    // ---- compute: 2 k-slices x 16 MFMA ----
#pragma unroll
    for (int ks = 0; ks < 2; ks++) {
      bf16x8 af[4], bf[4];
      const int ch = ks * 4 + (lane >> 4);
#pragma unroll
      for (int mi = 0; mi < 4; mi++) {
        int row = mi * 16 + (lane & 15);
        af[mi] = *(const bf16x8*)&Asm[row * 64 + (ch ^ (row & 7)) * 8];
      }
#pragma unroll
      for (int ni = 0; ni < 4; ni++) {
        int n = w * 64 + ni * 16 + (lane & 15);
        bf[ni] = *(const bf16x8*)&Bsm[n * 64 + (ch ^ (n & 7)) * 8];
      }
#pragma unroll
      for (int mi = 0; mi < 4; mi++)
#pragma unroll
        for (int ni = 0; ni < 4; ni++)
          acc[mi][ni] = __builtin_amdgcn_mfma_f32_16x16x32_bf16(af[mi], bf[ni], acc[mi][ni], 0, 0, 0);
    }
#pragma unroll
    for (int j = 0; j < 4; j++) a0[j] = a1[j];
  }
  // ---- epilogue ----
#pragma unroll
  for (int mi = 0; mi < 4; mi++)
#pragma unroll
    for (int ni = 0; ni < 4; ni++) {
      int col = w * 64 + ni * 16 + (lane & 15);
#pragma unroll
      for (int j = 0; j < 4; j++) {
        int row = mi * 16 + (lane >> 4) * 4 + j;
        Cg[(size_t)row * Fc + col] = acc[mi][ni][j];
      }
    }
}

// ---------------------------------------------------------------------------
// K3: h1 = [sum_kh aggP | x[d2d1]] @ w1 ; raw score1 = h1 . att_vec[0:128]
// ---------------------------------------------------------------------------
__global__ __launch_bounds__(128, 4)
void k3_h1(const float* __restrict__ aggP, const float* __restrict__ feat,
           const int* __restrict__ srcn, const int* __restrict__ d2d1,
           const float* __restrict__ wmat, const float* __restrict__ attv,
           float* __restrict__ h1, float* __restrict__ score1, int KH) {
  const int rel = blockIdx.y, d0 = blockIdx.x * 8, t = threadIdx.x;
  __shared__ float rows[8][512];
#pragma unroll
  for (int i = 0; i < 8; i++) {
    const int d = d0 + i;
    if (t < 64) {
      const int f = t * 4;
      float4 v; v.x = v.y = v.z = v.w = 0.f;
      for (int p = 0; p < KH; p++) {
        float4 u = *(const float4*)(aggP + (((size_t)p * Rc + rel) * D1c + d) * Fc + f);
        v.x += u.x; v.y += u.y; v.z += u.z; v.w += u.w;
      }
      *(float4*)&rows[i][f] = v;
    } else {
      const int f = (t - 64) * 4;
      const int node = srcn[rel * N0c + d2d1[rel * D1c + d]];
      float4 v = *(const float4*)(feat + (size_t)node * Fc + f);
      *(float4*)&rows[i][256 + f] = v;
    }
  }
  __syncthreads();
  float acc[8] = {0, 0, 0, 0, 0, 0, 0, 0};
  for (int k = 0; k < 512; k += 4) {
    const float w0 = wmat[(k + 0) * Hc + t];
    const float w1v = wmat[(k + 1) * Hc + t];
    const float w2v = wmat[(k + 2) * Hc + t];
    const float w3v = wmat[(k + 3) * Hc + t];
#pragma unroll
    for (int i = 0; i < 8; i++) {
      float4 rv = *(const float4*)&rows[i][k];
      acc[i] += rv.x * w0 + rv.y * w1v + rv.z * w2v + rv.w * w3v;
    }
  }
#pragma unroll
  for (int i = 0; i < 8; i++)
    h1[((size_t)rel * D1c + d0 + i) * Hc + t] = acc[i];
  const float avt = attv[t];
  __shared__ float sred[2][8];
#pragma unroll
  for (int i = 0; i < 8; i++) {
    float p = acc[i] * avt;
    p += __shfl_down(p, 32); p += __shfl_down(p, 16); p += __shfl_down(p, 8);
    p += __shfl_down(p, 4);  p += __shfl_down(p, 2);  p += __shfl_down(p, 1);
    if ((t & 63) == 0) sred[t >> 6][i] = p;
  }
  __syncthreads();
  if (t < 8) score1[rel * D1c + d0 + t] = sred[0][t] + sred[1][t];
}

// ---------------------------------------------------------------------------
// K4: softmax over 4096 scores per relation (in place)
// ---------------------------------------------------------------------------
__global__ __launch_bounds__(1024, 1)
void k4_softmax1(float* __restrict__ score1) {
  const int rel = blockIdx.x, t = threadIdx.x;
  float* s = score1 + rel * D1c;
  float v[4], m = -INFINITY;
#pragma unroll
  for (int j = 0; j < 4; j++) { v[j] = s[t + j * 1024]; m = fmaxf(m, v[j]); }
  __shared__ float red[1024];
  red[t] = m; __syncthreads();
  for (int off = 512; off > 0; off >>= 1) {
    if (t < off) red[t] = fmaxf(red[t], red[t + off]);
    __syncthreads();
  }
  const float M = red[0];
  __syncthreads();
  float e[4], sum = 0.f;
#pragma unroll
  for (int j = 0; j < 4; j++) { e[j] = expf(v[j] - M); sum += e[j]; }
  red[t] = sum; __syncthreads();
  for (int off = 512; off > 0; off >>= 1) {
    if (t < off) red[t] += red[t + off];
    __syncthreads();
  }
  const float inv = 1.0f / red[0];
#pragma unroll
  for (int j = 0; j < 4; j++) s[t + j * 1024] = e[j] * inv;
}

// ---------------------------------------------------------------------------
// K5: x1 = h1 * att1 (row-broadcast scale)
// ---------------------------------------------------------------------------
__global__ __launch_bounds__(256, 1)
void k5_scale1(const float* __restrict__ h1, const float* __restrict__ att1,
               float* __restrict__ x1) {
  const size_t i = ((size_t)blockIdx.x * 256 + threadIdx.x) * 4;
  float4 h = *(const float4*)(h1 + i);
  const float a = att1[i >> 7];
  float4 o; o.x = h.x * a; o.y = h.y * a; o.z = h.z * a; o.w = h.w * a;
  *(float4*)(x1 + i) = o;
}

// ---------------------------------------------------------------------------
// K6: agg2P[sp][r][d][h] = sum_{s in quarter sp} dif2[r][d][s]*x1[r][d2s2[s]][h]
//     s-dim split 4 ways (blockIdx.z) for occupancy; partials summed in k7.
// ---------------------------------------------------------------------------
__global__ __launch_bounds__(256, 2)
void k6_gemm2(const float* __restrict__ dif2, const int* __restrict__ d2s2,
              const float* __restrict__ x1, float* __restrict__ agg2P) {
  const int rel = blockIdx.y, d0 = blockIdx.x * 16, sp = blockIdx.z;
  const int t = threadIdx.x, th = t & 127, g = t >> 7;
  __shared__ float dt[16][256];
  __shared__ int   sidx[256];
  __shared__ float red[16][128];
  float acc[16] = {};
  const float* x1r = x1 + (size_t)rel * D1c * Hc;
#pragma unroll 1
  for (int c = sp * 4; c < sp * 4 + 4; c++) {
    const int sb = c * 256;
    __syncthreads();
    {
      const int i = t >> 4, ko = (t & 15) * 16;
      const float* dp = dif2 + ((size_t)rel * D2c + d0 + i) * S2c + sb + ko;
      float4 q0 = ((const float4*)dp)[0];
      float4 q1 = ((const float4*)dp)[1];
      float4 q2 = ((const float4*)dp)[2];
      float4 q3 = ((const float4*)dp)[3];
      *(float4*)&dt[i][ko]      = q0;
      *(float4*)&dt[i][ko + 4]  = q1;
      *(float4*)&dt[i][ko + 8]  = q2;
      *(float4*)&dt[i][ko + 12] = q3;
    }
    sidx[t] = d2s2[rel * S2c + sb + t];
    __syncthreads();
#pragma unroll 4
    for (int jj = 0; jj < 128; jj++) {
      const int j = g * 128 + jj;
      const int row = sidx[j];
      const float xv = x1r[(size_t)row * Hc + th];
#pragma unroll
      for (int i = 0; i < 16; i++) acc[i] += dt[i][j] * xv;
    }
  }
  if (g == 1) {
#pragma unroll
    for (int i = 0; i < 16; i++) red[i][th] = acc[i];
  }
  __syncthreads();
  if (g == 0) {
#pragma unroll
    for (int i = 0; i < 16; i++)
      agg2P[(((size_t)sp * Rc + rel) * D2c + d0 + i) * Hc + th] = acc[i] + red[i][th];
  }
}

// ---------------------------------------------------------------------------
// K7: h2 = [sum_sp agg2P | x1[d2d2]] @ w2 ; raw score2
// ---------------------------------------------------------------------------
__global__ __launch_bounds__(128, 4)
void k7_h2(const float* __restrict__ agg2P, const float* __restrict__ x1,
           const int* __restrict__ d2d2, const float* __restrict__ wmat,
           const float* __restrict__ attv, float* __restrict__ h2,
           float* __restrict__ score2) {
  const int rel = blockIdx.y, d0 = blockIdx.x * 8, t = threadIdx.x;
  __shared__ float rows[8][256];
#pragma unroll
  for (int i = 0; i < 8; i++) {
    const int d = d0 + i;
    if (t < 64) {
      const int f = t * 2;
      float2 v; v.x = v.y = 0.f;
#pragma unroll
      for (int p = 0; p < 4; p++) {
        float2 u = *(const float2*)(agg2P + (((size_t)p * Rc + rel) * D2c + d) * Hc + f);
        v.x += u.x; v.y += u.y;
      }
      *(float2*)&rows[i][f] = v;
    } else {
      const int f = (t - 64) * 2;
      const int rrow = d2d2[rel * D2c + d];
      *(float2*)&rows[i][128 + f] = *(const float2*)(x1 + ((size_t)rel * D1c + rrow) * Hc + f);
    }
  }
  __syncthreads();
  float acc[8] = {0, 0, 0, 0, 0, 0, 0, 0};
  for (int k = 0; k < 256; k += 4) {
    const float w0 = wmat[(k + 0) * Hc + t];
    const float w1v = wmat[(k + 1) * Hc + t];
    const float w2v = wmat[(k + 2) * Hc + t];
    const float w3v = wmat[(k + 3) * Hc + t];
#pragma unroll
    for (int i = 0; i < 8; i++) {
      float4 rv = *(const float4*)&rows[i][k];
      acc[i] += rv.x * w0 + rv.y * w1v + rv.z * w2v + rv.w * w3v;
    }
  }
#pragma unroll
  for (int i = 0; i < 8; i++)
    h2[((size_t)rel * D2c + d0 + i) * Hc + t] = acc[i];
  const float avt = attv[t];
  __shared__ float sred[2][8];
#pragma unroll
  for (int i = 0; i < 8; i++) {
    float p = acc[i] * avt;
    p += __shfl_down(p, 32); p += __shfl_down(p, 16); p += __shfl_down(p, 8);
    p += __shfl_down(p, 4);  p += __shfl_down(p, 2);  p += __shfl_down(p, 1);
    if ((t & 63) == 0) sred[t >> 6][i] = p;
  }
  __syncthreads();
  if (t < 8) score2[rel * D2c + d0 + t] = sred[0][t] + sred[1][t];
}

// ---------------------------------------------------------------------------
// K8: softmax over 512 scores per relation (in place)
// ---------------------------------------------------------------------------
__global__ __launch_bounds__(512, 1)
void k8_softmax2(float* __restrict__ score2) {
  const int rel = blockIdx.x, t = threadIdx.x;
  float* s = score2 + rel * D2c;
  const float v = s[t];
  __shared__ float red[512];
  red[t] = v; __syncthreads();
  for (int off = 256; off > 0; off >>= 1) {
    if (t < off) red[t] = fmaxf(red[t], red[t + off]);
    __syncthreads();
  }
  const float M = red[0];
  __syncthreads();
  const float e = expf(v - M);
  red[t] = e; __syncthreads();
  for (int off = 256; off > 0; off >>= 1) {
    if (t < off) red[t] += red[t + off];
    __syncthreads();
  }
  s[t] = e / red[0];
}

// ---------------------------------------------------------------------------
// K9: summed = sum_r h2*att2 ; l2-normalize row; logits = normed@cw; softmax
// ---------------------------------------------------------------------------
__global__ __launch_bounds__(128, 4)
void k9_final(const float* __restrict__ h2, const float* __restrict__ att2,
              const float* __restrict__ cw, float* __restrict__ out) {
  const int d = blockIdx.x, t = threadIdx.x;
  float v = 0.f;
#pragma unroll
  for (int r = 0; r < Rc; r++)
    v += h2[((size_t)r * D2c + d) * Hc + t] * att2[r * D2c + d];
  float ss = v * v;
  ss += __shfl_down(ss, 32); ss += __shfl_down(ss, 16); ss += __shfl_down(ss, 8);
  ss += __shfl_down(ss, 4);  ss += __shfl_down(ss, 2);  ss += __shfl_down(ss, 1);
  __shared__ float sr[3][2];
  if ((t & 63) == 0) sr[0][t >> 6] = ss;
  __syncthreads();
  const float tot = sr[0][0] + sr[0][1];
  const float inv = rsqrtf(fmaxf(tot, 1e-12f));
  const float nv = v * inv;
  float p0 = nv * cw[t * 2], p1 = nv * cw[t * 2 + 1];
  p0 += __shfl_down(p0, 32); p0 += __shfl_down(p0, 16); p0 += __shfl_down(p0, 8);
  p0 += __shfl_down(p0, 4);  p0 += __shfl_down(p0, 2);  p0 += __shfl_down(p0, 1);
  p1 += __shfl_down(p1, 32); p1 += __shfl_down(p1, 16); p1 += __shfl_down(p1, 8);
  p1 += __shfl_down(p1, 4);  p1 += __shfl_down(p1, 2);  p1 += __shfl_down(p1, 1);
  if ((t & 63) == 0) { sr[1][t >> 6] = p0; sr[2][t >> 6] = p1; }
  __syncthreads();
  if (t == 0) {
    const float l0 = sr[1][0] + sr[1][1];
    const float l1 = sr[2][0] + sr[2][1];
    const float m = fmaxf(l0, l1);
    const float e0 = expf(l0 - m), e1 = expf(l1 - m);
    const float is = 1.0f / (e0 + e1);
    out[d * 2 + 0] = e0 * is;
    out[d * 2 + 1] = e1 * is;
  }
}

// ---------------------------------------------------------------------------
extern "C" void kernel_launch(void* const* d_in, const int* in_sizes, int n_in,
                              void* d_out, int out_size, void* d_ws, size_t ws_size,
                              hipStream_t stream) {
  (void)in_sizes; (void)n_in; (void)out_size;
  const float* feat = (const float*)d_in[0];
  const int*   srcn = (const int*)d_in[1];
  const int*   d2s1 = (const int*)d_in[2];
  const int*   d2d1 = (const int*)d_in[3];
  const float* dif1 = (const float*)d_in[4];
  const int*   d2s2 = (const int*)d_in[5];
  const int*   d2d2 = (const int*)d_in[6];
  const float* dif2 = (const float*)d_in[7];
  const float* w1   = (const float*)d_in[8];
  const float* w2   = (const float*)d_in[9];
  // d_in[10] relation_vectors: softmax-invariant constant -> unused.
  const float* attv = (const float*)d_in[11];
  const float* cw   = (const float*)d_in[12];
  float* out = (float*)d_out;

  // workspace budget: pick largest KH in {4,2,1} that fits
  const size_t szXgT  = (size_t)Rc * Fc * S1c * 2;          // 25.2 MB
  const size_t szTail = (size_t)Rc * D1c * Hc * 4 * 2       // h1 + x1
                      + (size_t)Rc * D1c * 4                // score1
                      + (size_t)4 * Rc * D2c * Hc * 4       // agg2P
                      + (size_t)Rc * D2c * Hc * 4           // h2
                      + (size_t)Rc * D2c * 4                // score2
                      + 16384;                              // align slack
  int KH = 4;
  while (KH > 1 && szXgT + (size_t)KH * Rc * D1c * Fc * 4 + szTail > ws_size)
    KH >>= 1;

  char* p = (char*)d_ws;
  auto take = [&](size_t n) { char* r = p; p += (n + 255) & ~(size_t)255; return r; };
  __bf16* xgT   = (__bf16*)take(szXgT);
  float*  aggP  = (float*) take((size_t)KH * Rc * D1c * Fc * 4);
  float*  h1    = (float*) take((size_t)Rc * D1c * Hc * 4);
  float*  score1= (float*) take((size_t)Rc * D1c * 4);
  float*  x1    = (float*) take((size_t)Rc * D1c * Hc * 4);
  float*  agg2P = (float*) take((size_t)4 * Rc * D2c * Hc * 4);
  float*  h2    = (float*) take((size_t)Rc * D2c * Hc * 4);
  float*  score2= (float*) take((size_t)Rc * D2c * 4);

  k1_gather_t<<<dim3(S1c / 64, Rc), 256, 0, stream>>>(feat, srcn, d2s1, xgT);
  k2_gemm1<<<dim3(D1c / 64, KH, Rc), 256, 0, stream>>>(dif1, xgT, aggP);
  k3_h1<<<dim3(D1c / 8, Rc), 128, 0, stream>>>(aggP, feat, srcn, d2d1, w1, attv, h1, score1, KH);
  k4_softmax1<<<Rc, 1024, 0, stream>>>(score1);
  k5_scale1<<<(Rc * D1c * Hc) / (256 * 4), 256, 0, stream>>>(h1, score1, x1);
  k6_gemm2<<<dim3(D2c / 16, Rc, 4), 256, 0, stream>>>(dif2, d2s2, x1, agg2P);
  k7_h2<<<dim3(D2c / 8, Rc), 128, 0, stream>>>(agg2P, x1, d2d2, w2, attv, h2, score2);
  k8_softmax2<<<Rc, 512, 0, stream>>>(score2);
  k9_final<<<D2c, 128, 0, stream>>>(h2, score2, cw, out);
}

// Round 3
// 299.816 us; speedup vs baseline: 2.1126x; 1.4383x over previous
//
#include <hip/hip_runtime.h>
#include <hip/hip_bf16.h>
#include <math.h>

constexpr int Rc  = 3;
constexpr int Fc  = 256;
constexpr int Hc  = 128;
constexpr int N0c = 16384;
constexpr int S1c = 16384;
constexpr int D1c = 4096;
constexpr int S2c = 4096;
constexpr int D2c = 512;
constexpr int KH1 = 4;    // K-split GEMM1
constexpr int KH2 = 16;   // K-split GEMM2

typedef __bf16 bf16x8 __attribute__((ext_vector_type(8)));
typedef float  f32x4  __attribute__((ext_vector_type(4)));

__device__ __forceinline__ void glds16(const void* g, void* l) {
  __builtin_amdgcn_global_load_lds(
      (const __attribute__((address_space(1))) void*)g,
      (__attribute__((address_space(3))) void*)l, 16, 0, 0);
}

__device__ __forceinline__ bf16x8 cvt2(const float4 a, const float4 b) {
  bf16x8 c;
  c[0] = (__bf16)a.x; c[1] = (__bf16)a.y; c[2] = (__bf16)a.z; c[3] = (__bf16)a.w;
  c[4] = (__bf16)b.x; c[5] = (__bf16)b.y; c[6] = (__bf16)b.z; c[7] = (__bf16)b.w;
  return c;
}

__device__ __forceinline__ unsigned short bfbits(float v) {
  __bf16 b = (__bf16)v; unsigned short u;
  __builtin_memcpy(&u, &b, 2); return u;
}

// ---------------------------------------------------------------------------
// wpack: fp32 weight [rows x 128] -> packed bf16 hi/lo B-panels in GEMM-LDS
// image: per 64-k tile: [n:128][cs:8][e:8] bf16, cs = ch ^ (n&7). 12 tiles:
// 0-3 w1top, 4-7 w1bot, 8-9 w2P, 10-11 w2Q. half=0 hi, half=1 lo (residual).
// ---------------------------------------------------------------------------
__global__ __launch_bounds__(256, 2)
void wpack(const float* __restrict__ w1, const float* __restrict__ w2,
           unsigned char* __restrict__ wp) {
  const int tile = blockIdx.x, half = blockIdx.y, t = threadIdx.x;
  const float* src; int row0;
  if (tile < 4)       { src = w1; row0 = tile * 64; }
  else if (tile < 8)  { src = w1; row0 = 256 + (tile - 4) * 64; }
  else if (tile < 10) { src = w2; row0 = (tile - 8) * 64; }
  else                { src = w2; row0 = 128 + (tile - 10) * 64; }
  unsigned char* dst = wp + ((size_t)half * 12 + tile) * 16384;
  __shared__ float sm[64][132];
  {
    const int r = t >> 2, c0 = (t & 3) * 32;
#pragma unroll
    for (int j = 0; j < 8; j++)
      *(float4*)&sm[r][c0 + 4 * j] = *(const float4*)(src + (size_t)(row0 + r) * 128 + c0 + 4 * j);
  }
  __syncthreads();
  if (t < 128) {
    const int n = t;
#pragma unroll
    for (int ch = 0; ch < 8; ch++) {
      bf16x8 o;
#pragma unroll
      for (int e = 0; e < 8; e++) {
        float v = sm[ch * 8 + e][n];
        __bf16 h = (__bf16)v;
        o[e] = half ? (__bf16)(v - (float)h) : h;
      }
      *(bf16x8*)(dst + n * 128 + ((ch ^ (n & 7)) * 16)) = o;
    }
  }
}

// ---------------------------------------------------------------------------
// gemm_gather: C = gather(A) * diag(scl) @ (Bhi + Blo)   [per-rel, N=128]
//   A rows fp32 (gathered via srcn[idx[...]] or direct), K in {256,128}.
//   out: fp32 row-major (Cf) or packed bf16 GEMM-B panel (Cp).
// ---------------------------------------------------------------------------
__global__ __launch_bounds__(256, 3)
void gemm_gather(const float* __restrict__ Abase, int astride,
                 const int* __restrict__ srcn, const int* __restrict__ idx,
                 const float* __restrict__ scl,
                 const unsigned char* __restrict__ Bh,
                 const unsigned char* __restrict__ Bl,
                 float* __restrict__ Cf, unsigned char* __restrict__ Cp,
                 int rows, int K) {
  const int rel = blockIdx.y, s0 = blockIdx.x * 64;
  const int t = threadIdx.x, lane = t & 63, w = t >> 6;
  const int NT = K >> 6;
  const int mh = w >> 1, nh = w & 1;

  __shared__ __bf16 Asm[64 * 64];      // 8 KB swizzled
  __shared__ __bf16 Bhs[128 * 64];     // 16 KB
  __shared__ __bf16 Bls[128 * 64];     // 16 KB

  const int arow = t >> 2, ak0 = (t & 3) * 16;
  const int row = s0 + arow;
  size_t arowg;
  if (idx) arowg = (size_t)srcn[rel * N0c + idx[(size_t)rel * rows + row]];
  else     arowg = (size_t)rel * rows + row;
  const float* aptr = Abase + arowg * astride + ak0;
  const float sc = scl ? scl[(size_t)rel * rows + row] : 1.0f;
  const int ac0 = ak0 >> 3;
  __bf16* asw0 = &Asm[arow * 64 + ((ac0    ) ^ (arow & 7)) * 8];
  __bf16* asw1 = &Asm[arow * 64 + ((ac0 + 1) ^ (arow & 7)) * 8];

  f32x4 acc[2][4] = {};

  for (int tl = 0; tl < NT; ++tl) {
    asm volatile("s_waitcnt lgkmcnt(0)" ::: "memory");
    __builtin_amdgcn_s_barrier();
    __builtin_amdgcn_sched_barrier(0);
    // stage B hi+lo tiles (4+4 glds per wave)
    {
      const unsigned char* bh = Bh + (size_t)tl * 16384 + w * 4096 + lane * 16;
      const unsigned char* bl = Bl + (size_t)tl * 16384 + w * 4096 + lane * 16;
      char* dh = (char*)Bhs + w * 4096;
      char* dl = (char*)Bls + w * 4096;
#pragma unroll
      for (int i = 0; i < 4; i++) glds16(bh + i * 1024, dh + i * 1024);
#pragma unroll
      for (int i = 0; i < 4; i++) glds16(bl + i * 1024, dl + i * 1024);
    }
    // stage A (gathered fp32 -> scale -> bf16)
    {
      float4 a[4];
#pragma unroll
      for (int j = 0; j < 4; j++) a[j] = *(const float4*)(aptr + tl * 64 + 4 * j);
      if (scl) {
#pragma unroll
        for (int j = 0; j < 4; j++) { a[j].x *= sc; a[j].y *= sc; a[j].z *= sc; a[j].w *= sc; }
      }
      *(bf16x8*)asw0 = cvt2(a[0], a[1]);
      *(bf16x8*)asw1 = cvt2(a[2], a[3]);
    }
    asm volatile("s_waitcnt vmcnt(0) lgkmcnt(0)" ::: "memory");
    __builtin_amdgcn_s_barrier();
    __builtin_amdgcn_sched_barrier(0);
#pragma unroll
    for (int ks = 0; ks < 2; ks++) {
      const int ch = ks * 4 + (lane >> 4);
      bf16x8 af[2], bh[4], bl[4];
#pragma unroll
      for (int mi = 0; mi < 2; mi++) {
        int r = mh * 32 + mi * 16 + (lane & 15);
        af[mi] = *(const bf16x8*)&Asm[r * 64 + ((ch ^ (r & 7)) * 8)];
      }
#pragma unroll
      for (int ni = 0; ni < 4; ni++) {
        int n = nh * 64 + ni * 16 + (lane & 15);
        bh[ni] = *(const bf16x8*)&Bhs[n * 64 + ((ch ^ (n & 7)) * 8)];
        bl[ni] = *(const bf16x8*)&Bls[n * 64 + ((ch ^ (n & 7)) * 8)];
      }
#pragma unroll
      for (int mi = 0; mi < 2; mi++)
#pragma unroll
        for (int ni = 0; ni < 4; ni++) {
          acc[mi][ni] = __builtin_amdgcn_mfma_f32_16x16x32_bf16(af[mi], bh[ni], acc[mi][ni], 0, 0, 0);
          acc[mi][ni] = __builtin_amdgcn_mfma_f32_16x16x32_bf16(af[mi], bl[ni], acc[mi][ni], 0, 0, 0);
        }
    }
  }
  // epilogue
  if (Cf) {
#pragma unroll
    for (int mi = 0; mi < 2; mi++)
#pragma unroll
      for (int ni = 0; ni < 4; ni++) {
        const int col = nh * 64 + ni * 16 + (lane & 15);
#pragma unroll
        for (int j = 0; j < 4; j++) {
          const int r = mh * 32 + mi * 16 + (lane >> 4) * 4 + j;
          Cf[((size_t)rel * rows + s0 + r) * 128 + col] = acc[mi][ni][j];
        }
      }
  } else {
    unsigned char* tile = Cp + ((size_t)(rel * (rows >> 6) + blockIdx.x)) * 16384;
#pragma unroll
    for (int mi = 0; mi < 2; mi++)
#pragma unroll
      for (int ni = 0; ni < 4; ni++) {
        const int sl0 = mh * 32 + mi * 16 + (lane >> 4) * 4;
        const int n = nh * 64 + ni * 16 + (lane & 15);
        const int ch = sl0 >> 3, e0 = sl0 & 7, cs = ch ^ (n & 7);
        ushort4 u;
        u.x = bfbits(acc[mi][ni][0]); u.y = bfbits(acc[mi][ni][1]);
        u.z = bfbits(acc[mi][ni][2]); u.w = bfbits(acc[mi][ni][3]);
        *(ushort4*)(tile + n * 128 + cs * 16 + e0 * 2) = u;
      }
  }
}

// ---------------------------------------------------------------------------
// gemm_big: C_partial[kh] = A[rel][m][k-slice] @ Bpanel   (N=128, BK=64)
//   A fp32 strided rows (dif mats, HBM-streamed); B pre-packed bf16 panels.
//   B double-buffered in LDS, glds issued one full iteration ahead;
//   A reg-double-buffered; counted vmcnt keeps prefetches in flight.
// ---------------------------------------------------------------------------
__global__ __launch_bounds__(256, 3)
void gemm_big(const float* __restrict__ A, const unsigned char* __restrict__ Bp,
              float* __restrict__ C, int M, int KTOT) {
  const int rel = blockIdx.z, kh = blockIdx.y;
  const int m0 = blockIdx.x * 64;
  const int t = threadIdx.x, lane = t & 63, w = t >> 6;
  const int KB = KTOT / gridDim.y, NT = KB >> 6;
  const int mh = w >> 1, nh = w & 1;

  const float* Ag = A + ((size_t)rel * M + m0) * KTOT + (size_t)kh * KB;
  const unsigned char* Bt = Bp + ((size_t)rel * (KTOT >> 6) + (size_t)kh * NT) * 16384;
  float* Cg = C + (((size_t)kh * Rc + rel) * M + m0) * 128;

  __shared__ __bf16 Asm[64 * 64];        // 8 KB
  __shared__ __bf16 Bsm[2][128 * 64];    // 2 x 16 KB

  f32x4 acc[2][4] = {};
  const int arow = t >> 2, ak0 = (t & 3) * 16;
  const float* aptr = Ag + (size_t)arow * KTOT + ak0;
  const int ac0 = ak0 >> 3;
  __bf16* asw0 = &Asm[arow * 64 + ((ac0    ) ^ (arow & 7)) * 8];
  __bf16* asw1 = &Asm[arow * 64 + ((ac0 + 1) ^ (arow & 7)) * 8];
  const unsigned char* bsrc = Bt + w * 4096 + lane * 16;

  float4 a0[4], a1[4];
#pragma unroll
  for (int j = 0; j < 4; j++) a0[j] = *(const float4*)(aptr + 4 * j);
  {
    char* bd = (char*)Bsm[0] + w * 4096;
#pragma unroll
    for (int i = 0; i < 4; i++) glds16(bsrc + i * 1024, bd + i * 1024);
  }

  for (int tl = 0; tl < NT; ++tl) {
    const int cur = tl & 1;
    asm volatile("s_waitcnt lgkmcnt(0)" ::: "memory");
    __builtin_amdgcn_s_barrier();
    __builtin_amdgcn_sched_barrier(0);
    if (tl + 1 < NT) {
      const unsigned char* bs = bsrc + (size_t)(tl + 1) * 16384;
      char* bd = (char*)Bsm[cur ^ 1] + w * 4096;
#pragma unroll
      for (int i = 0; i < 4; i++) glds16(bs + i * 1024, bd + i * 1024);
      const float* ap = aptr + (size_t)(tl + 1) * 64;
#pragma unroll
      for (int j = 0; j < 4; j++) a1[j] = *(const float4*)(ap + 4 * j);
    }
    *(bf16x8*)asw0 = cvt2(a0[0], a0[1]);
    *(bf16x8*)asw1 = cvt2(a0[2], a0[3]);
    if (tl + 1 < NT)
      asm volatile("s_waitcnt vmcnt(8) lgkmcnt(0)" ::: "memory");
    else
      asm volatile("s_waitcnt vmcnt(0) lgkmcnt(0)" ::: "memory");
    __builtin_amdgcn_s_barrier();
    __builtin_amdgcn_sched_barrier(0);
    const __bf16* Bc = Bsm[cur];
#pragma unroll
    for (int ks = 0; ks < 2; ks++) {
      const int ch = ks * 4 + (lane >> 4);
      bf16x8 af[2], bfr[4];
#pragma unroll
      for (int mi = 0; mi < 2; mi++) {
        int r = mh * 32 + mi * 16 + (lane & 15);
        af[mi] = *(const bf16x8*)&Asm[r * 64 + ((ch ^ (r & 7)) * 8)];
      }
#pragma unroll
      for (int ni = 0; ni < 4; ni++) {
        int n = nh * 64 + ni * 16 + (lane & 15);
        bfr[ni] = *(const bf16x8*)&Bc[n * 64 + ((ch ^ (n & 7)) * 8)];
      }
#pragma unroll
      for (int mi = 0; mi < 2; mi++)
#pragma unroll
        for (int ni = 0; ni < 4; ni++)
          acc[mi][ni] = __builtin_amdgcn_mfma_f32_16x16x32_bf16(af[mi], bfr[ni], acc[mi][ni], 0, 0, 0);
    }
#pragma unroll
    for (int j = 0; j < 4; j++) a0[j] = a1[j];
  }
#pragma unroll
  for (int mi = 0; mi < 2; mi++)
#pragma unroll
    for (int ni = 0; ni < 4; ni++) {
      const int col = nh * 64 + ni * 16 + (lane & 15);
#pragma unroll
      for (int j = 0; j < 4; j++) {
        const int r = mh * 32 + mi * 16 + (lane >> 4) * 4 + j;
        Cg[(size_t)r * 128 + col] = acc[mi][ni][j];
      }
    }
}

// ---------------------------------------------------------------------------
// pgpack: PG panel (GEMM2 B) <- gather P rows via d2s2, bf16, packed/swizzled
// ---------------------------------------------------------------------------
__global__ __launch_bounds__(256, 2)
void pgpack(const float* __restrict__ P, const int* __restrict__ d2s2,
            unsigned char* __restrict__ PGp) {
  const int rel = blockIdx.y, kb = blockIdx.x, t = threadIdx.x;
  __shared__ __bf16 sm[64][136];
  {
    const int kl = t >> 2, c0 = (t & 3) * 32;
    const int sr = d2s2[rel * S2c + kb * 64 + kl];
    const float4* p = (const float4*)(P + ((size_t)rel * D1c + sr) * 128 + c0);
#pragma unroll
    for (int j = 0; j < 4; j++)
      *(bf16x8*)&sm[kl][c0 + 8 * j] = cvt2(p[2 * j], p[2 * j + 1]);
  }
  __syncthreads();
  if (t < 128) {
    const int n = t;
    unsigned char* dst = PGp + ((size_t)(rel * (S2c >> 6) + kb)) * 16384;
#pragma unroll
    for (int ch = 0; ch < 8; ch++) {
      bf16x8 o;
#pragma unroll
      for (int e = 0; e < 8; e++) o[e] = sm[ch * 8 + e][n];
      *(bf16x8*)(dst + n * 128 + ((ch ^ (n & 7)) * 16)) = o;
    }
  }
}

// ---------------------------------------------------------------------------
// combine1: h1 = sum_kh aggP + xdw ; score1 = h1 . attv[0:128]
// ---------------------------------------------------------------------------
__global__ __launch_bounds__(128, 4)
void combine1(const float* __restrict__ aggP, const float* __restrict__ xdw,
              const float* __restrict__ attv, float* __restrict__ h1,
              float* __restrict__ score1) {
  const int rel = blockIdx.y, d0 = blockIdx.x * 8, t = threadIdx.x;
  float acc[8];
#pragma unroll
  for (int i = 0; i < 8; i++) {
    const int d = d0 + i;
    float v = xdw[((size_t)rel * D1c + d) * 128 + t];
#pragma unroll
    for (int p = 0; p < KH1; p++)
      v += aggP[(((size_t)p * Rc + rel) * D1c + d) * 128 + t];
    acc[i] = v;
    h1[((size_t)rel * D1c + d) * 128 + t] = v;
  }
  const float avt = attv[t];
  __shared__ float sred[2][8];
#pragma unroll
  for (int i = 0; i < 8; i++) {
    float p = acc[i] * avt;
    p += __shfl_down(p, 32); p += __shfl_down(p, 16); p += __shfl_down(p, 8);
    p += __shfl_down(p, 4);  p += __shfl_down(p, 2);  p += __shfl_down(p, 1);
    if ((t & 63) == 0) sred[t >> 6][i] = p;
  }
  __syncthreads();
  if (t < 8) score1[rel * D1c + d0 + t] = sred[0][t] + sred[1][t];
}

// ---------------------------------------------------------------------------
// combine2: h2 = sum_kh2 aggP2 + Q[d2d2] ; score2 = h2 . attv[0:128]
// ---------------------------------------------------------------------------
__global__ __launch_bounds__(128, 4)
void combine2(const float* __restrict__ aggP2, const float* __restrict__ Q,
              const int* __restrict__ d2d2, const float* __restrict__ attv,
              float* __restrict__ h2, float* __restrict__ score2) {
  const int rel = blockIdx.y, d0 = blockIdx.x * 8, t = threadIdx.x;
  float acc[8];
#pragma unroll
  for (int i = 0; i < 8; i++) {
    const int d = d0 + i;
    const int qr = d2d2[rel * D2c + d];
    float v = Q[((size_t)rel * D1c + qr) * 128 + t];
#pragma unroll
    for (int p = 0; p < KH2; p++)
      v += aggP2[(((size_t)p * Rc + rel) * D2c + d) * 128 + t];
    acc[i] = v;
    h2[((size_t)rel * D2c + d) * 128 + t] = v;
  }
  const float avt = attv[t];
  __shared__ float sred[2][8];
#pragma unroll
  for (int i = 0; i < 8; i++) {
    float p = acc[i] * avt;
    p += __shfl_down(p, 32); p += __shfl_down(p, 16); p += __shfl_down(p, 8);
    p += __shfl_down(p, 4);  p += __shfl_down(p, 2);  p += __shfl_down(p, 1);
    if ((t & 63) == 0) sred[t >> 6][i] = p;
  }
  __syncthreads();
  if (t < 8) score2[rel * D2c + d0 + t] = sred[0][t] + sred[1][t];
}

// ---------------------------------------------------------------------------
// softmax kernels (in place)
// ---------------------------------------------------------------------------
__global__ __launch_bounds__(1024, 1)
void k4_softmax1(float* __restrict__ score1) {
  const int rel = blockIdx.x, t = threadIdx.x;
  float* s = score1 + rel * D1c;
  float v[4], m = -INFINITY;
#pragma unroll
  for (int j = 0; j < 4; j++) { v[j] = s[t + j * 1024]; m = fmaxf(m, v[j]); }
  __shared__ float red[1024];
  red[t] = m; __syncthreads();
  for (int off = 512; off > 0; off >>= 1) {
    if (t < off) red[t] = fmaxf(red[t], red[t + off]);
    __syncthreads();
  }
  const float M = red[0];
  __syncthreads();
  float e[4], sum = 0.f;
#pragma unroll
  for (int j = 0; j < 4; j++) { e[j] = expf(v[j] - M); sum += e[j]; }
  red[t] = sum; __syncthreads();
  for (int off = 512; off > 0; off >>= 1) {
    if (t < off) red[t] += red[t + off];
    __syncthreads();
  }
  const float inv = 1.0f / red[0];
#pragma unroll
  for (int j = 0; j < 4; j++) s[t + j * 1024] = e[j] * inv;
}

__global__ __launch_bounds__(512, 1)
void k8_softmax2(float* __restrict__ score2) {
  const int rel = blockIdx.x, t = threadIdx.x;
  float* s = score2 + rel * D2c;
  const float v = s[t];
  __shared__ float red[512];
  red[t] = v; __syncthreads();
  for (int off = 256; off > 0; off >>= 1) {
    if (t < off) red[t] = fmaxf(red[t], red[t + off]);
    __syncthreads();
  }
  const float M = red[0];
  __syncthreads();
  const float e = expf(v - M);
  red[t] = e; __syncthreads();
  for (int off = 256; off > 0; off >>= 1) {
    if (t < off) red[t] += red[t + off];
    __syncthreads();
  }
  s[t] = e / red[0];
}

// ---------------------------------------------------------------------------
// k9: summed = sum_r h2*att2 ; l2-normalize; logits = normed@cw; softmax
// ---------------------------------------------------------------------------
__global__ __launch_bounds__(128, 4)
void k9_final(const float* __restrict__ h2, const float* __restrict__ att2,
              const float* __restrict__ cw, float* __restrict__ out) {
  const int d = blockIdx.x, t = threadIdx.x;
  float v = 0.f;
#pragma unroll
  for (int r = 0; r < Rc; r++)
    v += h2[((size_t)r * D2c + d) * Hc + t] * att2[r * D2c + d];
  float ss = v * v;
  ss += __shfl_down(ss, 32); ss += __shfl_down(ss, 16); ss += __shfl_down(ss, 8);
  ss += __shfl_down(ss, 4);  ss += __shfl_down(ss, 2);  ss += __shfl_down(ss, 1);
  __shared__ float sr[3][2];
  if ((t & 63) == 0) sr[0][t >> 6] = ss;
  __syncthreads();
  const float tot = sr[0][0] + sr[0][1];
  const float inv = rsqrtf(fmaxf(tot, 1e-12f));
  const float nv = v * inv;
  float p0 = nv * cw[t * 2], p1 = nv * cw[t * 2 + 1];
  p0 += __shfl_down(p0, 32); p0 += __shfl_down(p0, 16); p0 += __shfl_down(p0, 8);
  p0 += __shfl_down(p0, 4);  p0 += __shfl_down(p0, 2);  p0 += __shfl_down(p0, 1);
  p1 += __shfl_down(p1, 32); p1 += __shfl_down(p1, 16); p1 += __shfl_down(p1, 8);
  p1 += __shfl_down(p1, 4);  p1 += __shfl_down(p1, 2);  p1 += __shfl_down(p1, 1);
  if ((t & 63) == 0) { sr[1][t >> 6] = p0; sr[2][t >> 6] = p1; }
  __syncthreads();
  if (t == 0) {
    const float l0 = sr[1][0] + sr[1][1];
    const float l1 = sr[2][0] + sr[2][1];
    const float m = fmaxf(l0, l1);
    const float e0 = expf(l0 - m), e1 = expf(l1 - m);
    const float is = 1.0f / (e0 + e1);
    out[d * 2 + 0] = e0 * is;
    out[d * 2 + 1] = e1 * is;
  }
}

// ---------------------------------------------------------------------------
extern "C" void kernel_launch(void* const* d_in, const int* in_sizes, int n_in,
                              void* d_out, int out_size, void* d_ws, size_t ws_size,
                              hipStream_t stream) {
  (void)in_sizes; (void)n_in; (void)out_size; (void)ws_size;
  const float* feat = (const float*)d_in[0];
  const int*   srcn = (const int*)d_in[1];
  const int*   d2s1 = (const int*)d_in[2];
  const int*   d2d1 = (const int*)d_in[3];
  const float* dif1 = (const float*)d_in[4];
  const int*   d2s2 = (const int*)d_in[5];
  const int*   d2d2 = (const int*)d_in[6];
  const float* dif2 = (const float*)d_in[7];
  const float* w1   = (const float*)d_in[8];
  const float* w2   = (const float*)d_in[9];
  // d_in[10] relation_vectors: softmax-invariant constant -> unused.
  const float* attv = (const float*)d_in[11];
  const float* cw   = (const float*)d_in[12];
  float* out = (float*)d_out;

  char* p = (char*)d_ws;
  auto take = [&](size_t n) { char* r = p; p += (n + 255) & ~(size_t)255; return r; };
  unsigned char* wp   = (unsigned char*)take(24 * 16384);                 // 384 KB panels
  unsigned char* xgwp = (unsigned char*)take((size_t)Rc * 256 * 16384);   // 12.6 MB (reused as P|Q)
  float* xdw    = (float*)take((size_t)Rc * D1c * 128 * 4);               // 6.3 MB
  float* aggP   = (float*)take((size_t)KH1 * Rc * D1c * 128 * 4);         // 25.2 MB (reused as aggP2)
  float* h1     = (float*)take((size_t)Rc * D1c * 128 * 4);               // 6.3 MB
  float* score1 = (float*)take((size_t)Rc * D1c * 4);
  unsigned char* PGp = (unsigned char*)take((size_t)Rc * 64 * 16384);     // 3.15 MB
  float* h2     = (float*)take((size_t)Rc * D2c * 128 * 4);
  float* score2 = (float*)take((size_t)Rc * D2c * 4);
  // aliases (lifetimes disjoint, stream-ordered)
  float* P = (float*)xgwp;                       // after gemm_big #1
  float* Q = P + (size_t)Rc * D1c * 128;
  float* aggP2 = aggP;                           // after combine1

  const unsigned char* w1t_h = wp;                const unsigned char* w1t_l = wp + 12 * 16384;
  const unsigned char* w1b_h = wp + 4 * 16384;    const unsigned char* w1b_l = wp + 16 * 16384;
  const unsigned char* w2P_h = wp + 8 * 16384;    const unsigned char* w2P_l = wp + 20 * 16384;
  const unsigned char* w2Q_h = wp + 10 * 16384;   const unsigned char* w2Q_l = wp + 22 * 16384;

  wpack<<<dim3(12, 2), 256, 0, stream>>>(w1, w2, wp);
  // xgw = gather(feat; srcn.d2s1) @ w1top  -> packed B panel for GEMM1
  gemm_gather<<<dim3(S1c / 64, Rc), 256, 0, stream>>>(
      feat, Fc, srcn, d2s1, nullptr, w1t_h, w1t_l, nullptr, xgwp, S1c, 256);
  // xdw = gather(feat; srcn.d2d1) @ w1bot  -> fp32
  gemm_gather<<<dim3(D1c / 64, Rc), 256, 0, stream>>>(
      feat, Fc, srcn, d2d1, nullptr, w1b_h, w1b_l, xdw, nullptr, D1c, 256);
  // aggP[kh] = dif1 @ xgw   (the 768 MB HBM stream)
  gemm_big<<<dim3(D1c / 64, KH1, Rc), 256, 0, stream>>>(dif1, xgwp, aggP, D1c, S1c);
  combine1<<<dim3(D1c / 8, Rc), 128, 0, stream>>>(aggP, xdw, attv, h1, score1);
  k4_softmax1<<<Rc, 1024, 0, stream>>>(score1);
  // P = (h1*att1) @ w2top ; Q = (h1*att1) @ w2bot
  gemm_gather<<<dim3(D1c / 64, Rc), 256, 0, stream>>>(
      h1, Hc, nullptr, nullptr, score1, w2P_h, w2P_l, P, nullptr, D1c, 128);
  gemm_gather<<<dim3(D1c / 64, Rc), 256, 0, stream>>>(
      h1, Hc, nullptr, nullptr, score1, w2Q_h, w2Q_l, Q, nullptr, D1c, 128);
  pgpack<<<dim3(S2c / 64, Rc), 256, 0, stream>>>(P, d2s2, PGp);
  // aggP2[kh] = dif2 @ PG
  gemm_big<<<dim3(D2c / 64, KH2, Rc), 256, 0, stream>>>(dif2, PGp, aggP2, D2c, S2c);
  combine2<<<dim3(D2c / 8, Rc), 128, 0, stream>>>(aggP2, Q, d2d2, attv, h2, score2);
  k8_softmax2<<<Rc, 512, 0, stream>>>(score2);
  k9_final<<<D2c, 128, 0, stream>>>(h2, score2, cw, out);
}

// Round 4
// 285.015 us; speedup vs baseline: 2.2223x; 1.0519x over previous
//
#include <hip/hip_runtime.h>
#include <hip/hip_bf16.h>
#include <math.h>

constexpr int Rc  = 3;
constexpr int Fc  = 256;
constexpr int Hc  = 128;
constexpr int N0c = 16384;
constexpr int S1c = 16384;
constexpr int D1c = 4096;
constexpr int S2c = 4096;
constexpr int D2c = 512;
constexpr int KH1 = 4;    // K-split GEMM1 (hard-coded in swizzle decode)
constexpr int KH2 = 16;   // K-split GEMM2

typedef __bf16 bf16x8 __attribute__((ext_vector_type(8)));
typedef float  f32x4  __attribute__((ext_vector_type(4)));

__device__ __forceinline__ void glds16(const void* g, void* l) {
  __builtin_amdgcn_global_load_lds(
      (const __attribute__((address_space(1))) void*)g,
      (__attribute__((address_space(3))) void*)l, 16, 0, 0);
}

__device__ __forceinline__ bf16x8 cvt2(const float4 a, const float4 b) {
  bf16x8 c;
  c[0] = (__bf16)a.x; c[1] = (__bf16)a.y; c[2] = (__bf16)a.z; c[3] = (__bf16)a.w;
  c[4] = (__bf16)b.x; c[5] = (__bf16)b.y; c[6] = (__bf16)b.z; c[7] = (__bf16)b.w;
  return c;
}

__device__ __forceinline__ unsigned short bfbits(float v) {
  __bf16 b = (__bf16)v; unsigned short u;
  __builtin_memcpy(&u, &b, 2); return u;
}

// ---------------------------------------------------------------------------
// wpack: fp32 weight [rows x 128] -> packed bf16 hi/lo B-panels in GEMM-LDS
// image: per 64-k tile: [n:128][cs:8][e:8] bf16, cs = ch ^ (n&7). 12 tiles:
// 0-3 w1top, 4-7 w1bot, 8-9 w2P, 10-11 w2Q. half=0 hi, half=1 lo (residual).
// ---------------------------------------------------------------------------
__global__ __launch_bounds__(256, 2)
void wpack(const float* __restrict__ w1, const float* __restrict__ w2,
           unsigned char* __restrict__ wp) {
  const int tile = blockIdx.x, half = blockIdx.y, t = threadIdx.x;
  const float* src; int row0;
  if (tile < 4)       { src = w1; row0 = tile * 64; }
  else if (tile < 8)  { src = w1; row0 = 256 + (tile - 4) * 64; }
  else if (tile < 10) { src = w2; row0 = (tile - 8) * 64; }
  else                { src = w2; row0 = 128 + (tile - 10) * 64; }
  unsigned char* dst = wp + ((size_t)half * 12 + tile) * 16384;
  __shared__ float sm[64][132];
  {
    const int r = t >> 2, c0 = (t & 3) * 32;
#pragma unroll
    for (int j = 0; j < 8; j++)
      *(float4*)&sm[r][c0 + 4 * j] = *(const float4*)(src + (size_t)(row0 + r) * 128 + c0 + 4 * j);
  }
  __syncthreads();
  if (t < 128) {
    const int n = t;
#pragma unroll
    for (int ch = 0; ch < 8; ch++) {
      bf16x8 o;
#pragma unroll
      for (int e = 0; e < 8; e++) {
        float v = sm[ch * 8 + e][n];
        __bf16 h = (__bf16)v;
        o[e] = half ? (__bf16)(v - (float)h) : h;
      }
      *(bf16x8*)(dst + n * 128 + ((ch ^ (n & 7)) * 16)) = o;
    }
  }
}

// ---------------------------------------------------------------------------
// gg_layer1: fused layer-1 projections (two jobs, split by blockIdx.x):
//   job0 (bx<256):  xgw = gather(feat; srcn.d2s1) @ (w1t_h+w1t_l) -> packed panel
//   job1 (bx>=256): xdw = gather(feat; srcn.d2d1) @ (w1b_h+w1b_l) -> fp32
// ---------------------------------------------------------------------------
__global__ __launch_bounds__(256, 3)
void gg_layer1(const float* __restrict__ feat, const int* __restrict__ srcn,
               const int* __restrict__ d2s1, const int* __restrict__ d2d1,
               const unsigned char* __restrict__ wp,
               unsigned char* __restrict__ xgwp, float* __restrict__ xdw) {
  const int rel = blockIdx.y;
  int bx = blockIdx.x;
  const int job = bx >= 256 ? 1 : 0;
  if (job) bx -= 256;
  const int s0 = bx * 64;
  const int rows = job ? D1c : S1c;
  const int* idx = job ? d2d1 : d2s1;
  const unsigned char* Bh = wp + (size_t)(job ? 4 : 0) * 16384;
  const unsigned char* Bl = wp + (size_t)(12 + (job ? 4 : 0)) * 16384;

  const int t = threadIdx.x, lane = t & 63, w = t >> 6;
  const int NT = 4;                       // K = 256
  const int mh = w >> 1, nh = w & 1;

  __shared__ __bf16 Asm[64 * 64];
  __shared__ __bf16 Bhs[128 * 64];
  __shared__ __bf16 Bls[128 * 64];

  const int arow = t >> 2, ak0 = (t & 3) * 16;
  const int row = s0 + arow;
  const size_t arowg = (size_t)srcn[rel * N0c + idx[(size_t)rel * rows + row]];
  const float* aptr = feat + arowg * Fc + ak0;
  const int ac0 = ak0 >> 3;
  __bf16* asw0 = &Asm[arow * 64 + ((ac0    ) ^ (arow & 7)) * 8];
  __bf16* asw1 = &Asm[arow * 64 + ((ac0 + 1) ^ (arow & 7)) * 8];

  f32x4 acc[2][4] = {};

  for (int tl = 0; tl < NT; ++tl) {
    asm volatile("s_waitcnt lgkmcnt(0)" ::: "memory");
    __builtin_amdgcn_s_barrier();
    __builtin_amdgcn_sched_barrier(0);
    {
      const unsigned char* bh = Bh + (size_t)tl * 16384 + w * 4096 + lane * 16;
      const unsigned char* bl = Bl + (size_t)tl * 16384 + w * 4096 + lane * 16;
      char* dh = (char*)Bhs + w * 4096;
      char* dl = (char*)Bls + w * 4096;
#pragma unroll
      for (int i = 0; i < 4; i++) glds16(bh + i * 1024, dh + i * 1024);
#pragma unroll
      for (int i = 0; i < 4; i++) glds16(bl + i * 1024, dl + i * 1024);
    }
    {
      float4 a[4];
#pragma unroll
      for (int j = 0; j < 4; j++) a[j] = *(const float4*)(aptr + tl * 64 + 4 * j);
      *(bf16x8*)asw0 = cvt2(a[0], a[1]);
      *(bf16x8*)asw1 = cvt2(a[2], a[3]);
    }
    asm volatile("s_waitcnt vmcnt(0) lgkmcnt(0)" ::: "memory");
    __builtin_amdgcn_s_barrier();
    __builtin_amdgcn_sched_barrier(0);
#pragma unroll
    for (int ks = 0; ks < 2; ks++) {
      const int ch = ks * 4 + (lane >> 4);
      bf16x8 af[2], bh[4], bl[4];
#pragma unroll
      for (int mi = 0; mi < 2; mi++) {
        int r = mh * 32 + mi * 16 + (lane & 15);
        af[mi] = *(const bf16x8*)&Asm[r * 64 + ((ch ^ (r & 7)) * 8)];
      }
#pragma unroll
      for (int ni = 0; ni < 4; ni++) {
        int n = nh * 64 + ni * 16 + (lane & 15);
        bh[ni] = *(const bf16x8*)&Bhs[n * 64 + ((ch ^ (n & 7)) * 8)];
        bl[ni] = *(const bf16x8*)&Bls[n * 64 + ((ch ^ (n & 7)) * 8)];
      }
#pragma unroll
      for (int mi = 0; mi < 2; mi++)
#pragma unroll
        for (int ni = 0; ni < 4; ni++) {
          acc[mi][ni] = __builtin_amdgcn_mfma_f32_16x16x32_bf16(af[mi], bh[ni], acc[mi][ni], 0, 0, 0);
          acc[mi][ni] = __builtin_amdgcn_mfma_f32_16x16x32_bf16(af[mi], bl[ni], acc[mi][ni], 0, 0, 0);
        }
    }
  }
  if (job) {
#pragma unroll
    for (int mi = 0; mi < 2; mi++)
#pragma unroll
      for (int ni = 0; ni < 4; ni++) {
        const int col = nh * 64 + ni * 16 + (lane & 15);
#pragma unroll
        for (int j = 0; j < 4; j++) {
          const int r = mh * 32 + mi * 16 + (lane >> 4) * 4 + j;
          xdw[((size_t)rel * D1c + s0 + r) * 128 + col] = acc[mi][ni][j];
        }
      }
  } else {
    unsigned char* tile = xgwp + ((size_t)(rel * (S1c >> 6) + bx)) * 16384;
#pragma unroll
    for (int mi = 0; mi < 2; mi++)
#pragma unroll
      for (int ni = 0; ni < 4; ni++) {
        const int sl0 = mh * 32 + mi * 16 + (lane >> 4) * 4;
        const int n = nh * 64 + ni * 16 + (lane & 15);
        const int ch = sl0 >> 3, e0 = sl0 & 7, cs = ch ^ (n & 7);
        ushort4 u;
        u.x = bfbits(acc[mi][ni][0]); u.y = bfbits(acc[mi][ni][1]);
        u.z = bfbits(acc[mi][ni][2]); u.w = bfbits(acc[mi][ni][3]);
        *(ushort4*)(tile + n * 128 + cs * 16 + e0 * 2) = u;
      }
  }
}

// ---------------------------------------------------------------------------
// gg_layer2: P = (h1*att1)@w2top (z=0), Q = (h1*att1)@w2bot (z=1). K=128.
// ---------------------------------------------------------------------------
__global__ __launch_bounds__(256, 3)
void gg_layer2(const float* __restrict__ h1, const float* __restrict__ scl,
               const unsigned char* __restrict__ wp,
               float* __restrict__ P, float* __restrict__ Q) {
  const int rel = blockIdx.y, s0 = blockIdx.x * 64, z = blockIdx.z;
  const unsigned char* Bh = wp + (size_t)(z ? 10 : 8) * 16384;
  const unsigned char* Bl = wp + (size_t)(z ? 22 : 20) * 16384;
  float* Cf = z ? Q : P;

  const int t = threadIdx.x, lane = t & 63, w = t >> 6;
  const int NT = 2;                       // K = 128
  const int mh = w >> 1, nh = w & 1;

  __shared__ __bf16 Asm[64 * 64];
  __shared__ __bf16 Bhs[128 * 64];
  __shared__ __bf16 Bls[128 * 64];

  const int arow = t >> 2, ak0 = (t & 3) * 16;
  const int row = s0 + arow;
  const float* aptr = h1 + ((size_t)rel * D1c + row) * Hc + ak0;
  const float sc = scl[(size_t)rel * D1c + row];
  const int ac0 = ak0 >> 3;
  __bf16* asw0 = &Asm[arow * 64 + ((ac0    ) ^ (arow & 7)) * 8];
  __bf16* asw1 = &Asm[arow * 64 + ((ac0 + 1) ^ (arow & 7)) * 8];

  f32x4 acc[2][4] = {};

  for (int tl = 0; tl < NT; ++tl) {
    asm volatile("s_waitcnt lgkmcnt(0)" ::: "memory");
    __builtin_amdgcn_s_barrier();
    __builtin_amdgcn_sched_barrier(0);
    {
      const unsigned char* bh = Bh + (size_t)tl * 16384 + w * 4096 + lane * 16;
      const unsigned char* bl = Bl + (size_t)tl * 16384 + w * 4096 + lane * 16;
      char* dh = (char*)Bhs + w * 4096;
      char* dl = (char*)Bls + w * 4096;
#pragma unroll
      for (int i = 0; i < 4; i++) glds16(bh + i * 1024, dh + i * 1024);
#pragma unroll
      for (int i = 0; i < 4; i++) glds16(bl + i * 1024, dl + i * 1024);
    }
    {
      float4 a[4];
#pragma unroll
      for (int j = 0; j < 4; j++) a[j] = *(const float4*)(aptr + tl * 64 + 4 * j);
#pragma unroll
      for (int j = 0; j < 4; j++) { a[j].x *= sc; a[j].y *= sc; a[j].z *= sc; a[j].w *= sc; }
      *(bf16x8*)asw0 = cvt2(a[0], a[1]);
      *(bf16x8*)asw1 = cvt2(a[2], a[3]);
    }
    asm volatile("s_waitcnt vmcnt(0) lgkmcnt(0)" ::: "memory");
    __builtin_amdgcn_s_barrier();
    __builtin_amdgcn_sched_barrier(0);
#pragma unroll
    for (int ks = 0; ks < 2; ks++) {
      const int ch = ks * 4 + (lane >> 4);
      bf16x8 af[2], bh[4], bl[4];
#pragma unroll
      for (int mi = 0; mi < 2; mi++) {
        int r = mh * 32 + mi * 16 + (lane & 15);
        af[mi] = *(const bf16x8*)&Asm[r * 64 + ((ch ^ (r & 7)) * 8)];
      }
#pragma unroll
      for (int ni = 0; ni < 4; ni++) {
        int n = nh * 64 + ni * 16 + (lane & 15);
        bh[ni] = *(const bf16x8*)&Bhs[n * 64 + ((ch ^ (n & 7)) * 8)];
        bl[ni] = *(const bf16x8*)&Bls[n * 64 + ((ch ^ (n & 7)) * 8)];
      }
#pragma unroll
      for (int mi = 0; mi < 2; mi++)
#pragma unroll
        for (int ni = 0; ni < 4; ni++) {
          acc[mi][ni] = __builtin_amdgcn_mfma_f32_16x16x32_bf16(af[mi], bh[ni], acc[mi][ni], 0, 0, 0);
          acc[mi][ni] = __builtin_amdgcn_mfma_f32_16x16x32_bf16(af[mi], bl[ni], acc[mi][ni], 0, 0, 0);
        }
    }
  }
#pragma unroll
  for (int mi = 0; mi < 2; mi++)
#pragma unroll
    for (int ni = 0; ni < 4; ni++) {
      const int col = nh * 64 + ni * 16 + (lane & 15);
#pragma unroll
      for (int j = 0; j < 4; j++) {
        const int r = mh * 32 + mi * 16 + (lane >> 4) * 4 + j;
        Cf[((size_t)rel * D1c + s0 + r) * 128 + col] = acc[mi][ni][j];
      }
    }
}

// ---------------------------------------------------------------------------
// gemm_big: C_partial[kh] = A[rel][m][k-slice] @ Bpanel   (N=128, BK=64)
//   SWZ=1: XCD-locality swizzle for the 768-block dif1 GEMM (KH1=4):
//   each XCD hosts 3 half-groups of 32 blocks -> per-XCD B footprint 3MB (L2).
// ---------------------------------------------------------------------------
template <int SWZ>
__global__ __launch_bounds__(256, 3)
void gemm_big(const float* __restrict__ A, const unsigned char* __restrict__ Bp,
              float* __restrict__ C, int M, int KTOT, int KH) {
  int rel, kh, m0;
  if (SWZ) {
    const int F = blockIdx.x;            // 768 blocks
    const int xcd = F & 7, r = F >> 3;   // r in [0,96)
    const int sub = r >> 5, m = r & 31;  // sub in [0,3)
    const int h = xcd + 8 * sub;         // half-group [0,24)
    const int g = h >> 1;                // group [0,12) = rel*4+kh
    rel = g >> 2; kh = g & 3;
    m0 = ((h & 1) * 32 + m) * 64;
  } else {
    rel = blockIdx.z; kh = blockIdx.y; m0 = blockIdx.x * 64;
  }
  const int t = threadIdx.x, lane = t & 63, w = t >> 6;
  const int KB = KTOT / KH, NT = KB >> 6;
  const int mh = w >> 1, nh = w & 1;

  const float* Ag = A + ((size_t)rel * M + m0) * KTOT + (size_t)kh * KB;
  const unsigned char* Bt = Bp + ((size_t)rel * (KTOT >> 6) + (size_t)kh * NT) * 16384;
  float* Cg = C + (((size_t)kh * Rc + rel) * M + m0) * 128;

  __shared__ __bf16 Asm[64 * 64];        // 8 KB
  __shared__ __bf16 Bsm[2][128 * 64];    // 2 x 16 KB

  f32x4 acc[2][4] = {};
  const int arow = t >> 2, ak0 = (t & 3) * 16;
  const float* aptr = Ag + (size_t)arow * KTOT + ak0;
  const int ac0 = ak0 >> 3;
  __bf16* asw0 = &Asm[arow * 64 + ((ac0    ) ^ (arow & 7)) * 8];
  __bf16* asw1 = &Asm[arow * 64 + ((ac0 + 1) ^ (arow & 7)) * 8];
  const unsigned char* bsrc = Bt + w * 4096 + lane * 16;

  float4 a0[4], a1[4];
#pragma unroll
  for (int j = 0; j < 4; j++) a0[j] = *(const float4*)(aptr + 4 * j);
  {
    char* bd = (char*)Bsm[0] + w * 4096;
#pragma unroll
    for (int i = 0; i < 4; i++) glds16(bsrc + i * 1024, bd + i * 1024);
  }

  for (int tl = 0; tl < NT; ++tl) {
    const int cur = tl & 1;
    asm volatile("s_waitcnt lgkmcnt(0)" ::: "memory");
    __builtin_amdgcn_s_barrier();
    __builtin_amdgcn_sched_barrier(0);
    if (tl + 1 < NT) {
      const unsigned char* bs = bsrc + (size_t)(tl + 1) * 16384;
      char* bd = (char*)Bsm[cur ^ 1] + w * 4096;
#pragma unroll
      for (int i = 0; i < 4; i++) glds16(bs + i * 1024, bd + i * 1024);
      const float* ap = aptr + (size_t)(tl + 1) * 64;
#pragma unroll
      for (int j = 0; j < 4; j++) a1[j] = *(const float4*)(ap + 4 * j);
    }
    *(bf16x8*)asw0 = cvt2(a0[0], a0[1]);
    *(bf16x8*)asw1 = cvt2(a0[2], a0[3]);
    if (tl + 1 < NT)
      asm volatile("s_waitcnt vmcnt(8) lgkmcnt(0)" ::: "memory");
    else
      asm volatile("s_waitcnt vmcnt(0) lgkmcnt(0)" ::: "memory");
    __builtin_amdgcn_s_barrier();
    __builtin_amdgcn_sched_barrier(0);
    const __bf16* Bc = Bsm[cur];
#pragma unroll
    for (int ks = 0; ks < 2; ks++) {
      const int ch = ks * 4 + (lane >> 4);
      bf16x8 af[2], bfr[4];
#pragma unroll
      for (int mi = 0; mi < 2; mi++) {
        int r = mh * 32 + mi * 16 + (lane & 15);
        af[mi] = *(const bf16x8*)&Asm[r * 64 + ((ch ^ (r & 7)) * 8)];
      }
#pragma unroll
      for (int ni = 0; ni < 4; ni++) {
        int n = nh * 64 + ni * 16 + (lane & 15);
        bfr[ni] = *(const bf16x8*)&Bc[n * 64 + ((ch ^ (n & 7)) * 8)];
      }
#pragma unroll
      for (int mi = 0; mi < 2; mi++)
#pragma unroll
        for (int ni = 0; ni < 4; ni++)
          acc[mi][ni] = __builtin_amdgcn_mfma_f32_16x16x32_bf16(af[mi], bfr[ni], acc[mi][ni], 0, 0, 0);
    }
#pragma unroll
    for (int j = 0; j < 4; j++) a0[j] = a1[j];
  }
#pragma unroll
  for (int mi = 0; mi < 2; mi++)
#pragma unroll
    for (int ni = 0; ni < 4; ni++) {
      const int col = nh * 64 + ni * 16 + (lane & 15);
#pragma unroll
      for (int j = 0; j < 4; j++) {
        const int r = mh * 32 + mi * 16 + (lane >> 4) * 4 + j;
        Cg[(size_t)r * 128 + col] = acc[mi][ni][j];
      }
    }
}

// ---------------------------------------------------------------------------
// pgpack: PG panel (GEMM2 B) <- gather P rows via d2s2, bf16, packed/swizzled
// ---------------------------------------------------------------------------
__global__ __launch_bounds__(256, 2)
void pgpack(const float* __restrict__ P, const int* __restrict__ d2s2,
            unsigned char* __restrict__ PGp) {
  const int rel = blockIdx.y, kb = blockIdx.x, t = threadIdx.x;
  __shared__ __bf16 sm[64][136];
  {
    const int kl = t >> 2, c0 = (t & 3) * 32;
    const int sr = d2s2[rel * S2c + kb * 64 + kl];
    const float4* p = (const float4*)(P + ((size_t)rel * D1c + sr) * 128 + c0);
#pragma unroll
    for (int j = 0; j < 4; j++)
      *(bf16x8*)&sm[kl][c0 + 8 * j] = cvt2(p[2 * j], p[2 * j + 1]);
  }
  __syncthreads();
  if (t < 128) {
    const int n = t;
    unsigned char* dst = PGp + ((size_t)(rel * (S2c >> 6) + kb)) * 16384;
#pragma unroll
    for (int ch = 0; ch < 8; ch++) {
      bf16x8 o;
#pragma unroll
      for (int e = 0; e < 8; e++) o[e] = sm[ch * 8 + e][n];
      *(bf16x8*)(dst + n * 128 + ((ch ^ (n & 7)) * 16)) = o;
    }
  }
}

// ---------------------------------------------------------------------------
// combine1: h1 = sum_kh aggP + xdw ; score1 = h1 . attv[0:128]
// ---------------------------------------------------------------------------
__global__ __launch_bounds__(128, 4)
void combine1(const float* __restrict__ aggP, const float* __restrict__ xdw,
              const float* __restrict__ attv, float* __restrict__ h1,
              float* __restrict__ score1) {
  const int rel = blockIdx.y, d0 = blockIdx.x * 8, t = threadIdx.x;
  float acc[8];
#pragma unroll
  for (int i = 0; i < 8; i++) {
    const int d = d0 + i;
    float v = xdw[((size_t)rel * D1c + d) * 128 + t];
#pragma unroll
    for (int p = 0; p < KH1; p++)
      v += aggP[(((size_t)p * Rc + rel) * D1c + d) * 128 + t];
    acc[i] = v;
    h1[((size_t)rel * D1c + d) * 128 + t] = v;
  }
  const float avt = attv[t];
  __shared__ float sred[2][8];
#pragma unroll
  for (int i = 0; i < 8; i++) {
    float p = acc[i] * avt;
    p += __shfl_down(p, 32); p += __shfl_down(p, 16); p += __shfl_down(p, 8);
    p += __shfl_down(p, 4);  p += __shfl_down(p, 2);  p += __shfl_down(p, 1);
    if ((t & 63) == 0) sred[t >> 6][i] = p;
  }
  __syncthreads();
  if (t < 8) score1[rel * D1c + d0 + t] = sred[0][t] + sred[1][t];
}

// ---------------------------------------------------------------------------
// combine2: h2 = sum_kh2 aggP2 + Q[d2d2] ; score2 = h2 . attv[0:128]
// ---------------------------------------------------------------------------
__global__ __launch_bounds__(128, 4)
void combine2(const float* __restrict__ aggP2, const float* __restrict__ Q,
              const int* __restrict__ d2d2, const float* __restrict__ attv,
              float* __restrict__ h2, float* __restrict__ score2) {
  const int rel = blockIdx.y, d0 = blockIdx.x * 8, t = threadIdx.x;
  float acc[8];
#pragma unroll
  for (int i = 0; i < 8; i++) {
    const int d = d0 + i;
    const int qr = d2d2[rel * D2c + d];
    float v = Q[((size_t)rel * D1c + qr) * 128 + t];
#pragma unroll
    for (int p = 0; p < KH2; p++)
      v += aggP2[(((size_t)p * Rc + rel) * D2c + d) * 128 + t];
    acc[i] = v;
    h2[((size_t)rel * D2c + d) * 128 + t] = v;
  }
  const float avt = attv[t];
  __shared__ float sred[2][8];
#pragma unroll
  for (int i = 0; i < 8; i++) {
    float p = acc[i] * avt;
    p += __shfl_down(p, 32); p += __shfl_down(p, 16); p += __shfl_down(p, 8);
    p += __shfl_down(p, 4);  p += __shfl_down(p, 2);  p += __shfl_down(p, 1);
    if ((t & 63) == 0) sred[t >> 6][i] = p;
  }
  __syncthreads();
  if (t < 8) score2[rel * D2c + d0 + t] = sred[0][t] + sred[1][t];
}

// ---------------------------------------------------------------------------
// softmax kernels (in place)
// ---------------------------------------------------------------------------
__global__ __launch_bounds__(1024, 1)
void k4_softmax1(float* __restrict__ score1) {
  const int rel = blockIdx.x, t = threadIdx.x;
  float* s = score1 + rel * D1c;
  float v[4], m = -INFINITY;
#pragma unroll
  for (int j = 0; j < 4; j++) { v[j] = s[t + j * 1024]; m = fmaxf(m, v[j]); }
  __shared__ float red[1024];
  red[t] = m; __syncthreads();
  for (int off = 512; off > 0; off >>= 1) {
    if (t < off) red[t] = fmaxf(red[t], red[t + off]);
    __syncthreads();
  }
  const float M = red[0];
  __syncthreads();
  float e[4], sum = 0.f;
#pragma unroll
  for (int j = 0; j < 4; j++) { e[j] = expf(v[j] - M); sum += e[j]; }
  red[t] = sum; __syncthreads();
  for (int off = 512; off > 0; off >>= 1) {
    if (t < off) red[t] += red[t + off];
    __syncthreads();
  }
  const float inv = 1.0f / red[0];
#pragma unroll
  for (int j = 0; j < 4; j++) s[t + j * 1024] = e[j] * inv;
}

__global__ __launch_bounds__(512, 1)
void k8_softmax2(float* __restrict__ score2) {
  const int rel = blockIdx.x, t = threadIdx.x;
  float* s = score2 + rel * D2c;
  const float v = s[t];
  __shared__ float red[512];
  red[t] = v; __syncthreads();
  for (int off = 256; off > 0; off >>= 1) {
    if (t < off) red[t] = fmaxf(red[t], red[t + off]);
    __syncthreads();
  }
  const float M = red[0];
  __syncthreads();
  const float e = expf(v - M);
  red[t] = e; __syncthreads();
  for (int off = 256; off > 0; off >>= 1) {
    if (t < off) red[t] += red[t + off];
    __syncthreads();
  }
  s[t] = e / red[0];
}

// ---------------------------------------------------------------------------
// k9: summed = sum_r h2*att2 ; l2-normalize; logits = normed@cw; softmax
// ---------------------------------------------------------------------------
__global__ __launch_bounds__(128, 4)
void k9_final(const float* __restrict__ h2, const float* __restrict__ att2,
              const float* __restrict__ cw, float* __restrict__ out) {
  const int d = blockIdx.x, t = threadIdx.x;
  float v = 0.f;
#pragma unroll
  for (int r = 0; r < Rc; r++)
    v += h2[((size_t)r * D2c + d) * Hc + t] * att2[r * D2c + d];
  float ss = v * v;
  ss += __shfl_down(ss, 32); ss += __shfl_down(ss, 16); ss += __shfl_down(ss, 8);
  ss += __shfl_down(ss, 4);  ss += __shfl_down(ss, 2);  ss += __shfl_down(ss, 1);
  __shared__ float sr[3][2];
  if ((t & 63) == 0) sr[0][t >> 6] = ss;
  __syncthreads();
  const float tot = sr[0][0] + sr[0][1];
  const float inv = rsqrtf(fmaxf(tot, 1e-12f));
  const float nv = v * inv;
  float p0 = nv * cw[t * 2], p1 = nv * cw[t * 2 + 1];
  p0 += __shfl_down(p0, 32); p0 += __shfl_down(p0, 16); p0 += __shfl_down(p0, 8);
  p0 += __shfl_down(p0, 4);  p0 += __shfl_down(p0, 2);  p0 += __shfl_down(p0, 1);
  p1 += __shfl_down(p1, 32); p1 += __shfl_down(p1, 16); p1 += __shfl_down(p1, 8);
  p1 += __shfl_down(p1, 4);  p1 += __shfl_down(p1, 2);  p1 += __shfl_down(p1, 1);
  if ((t & 63) == 0) { sr[1][t >> 6] = p0; sr[2][t >> 6] = p1; }
  __syncthreads();
  if (t == 0) {
    const float l0 = sr[1][0] + sr[1][1];
    const float l1 = sr[2][0] + sr[2][1];
    const float m = fmaxf(l0, l1);
    const float e0 = expf(l0 - m), e1 = expf(l1 - m);
    const float is = 1.0f / (e0 + e1);
    out[d * 2 + 0] = e0 * is;
    out[d * 2 + 1] = e1 * is;
  }
}

// ---------------------------------------------------------------------------
extern "C" void kernel_launch(void* const* d_in, const int* in_sizes, int n_in,
                              void* d_out, int out_size, void* d_ws, size_t ws_size,
                              hipStream_t stream) {
  (void)in_sizes; (void)n_in; (void)out_size; (void)ws_size;
  const float* feat = (const float*)d_in[0];
  const int*   srcn = (const int*)d_in[1];
  const int*   d2s1 = (const int*)d_in[2];
  const int*   d2d1 = (const int*)d_in[3];
  const float* dif1 = (const float*)d_in[4];
  const int*   d2s2 = (const int*)d_in[5];
  const int*   d2d2 = (const int*)d_in[6];
  const float* dif2 = (const float*)d_in[7];
  const float* w1   = (const float*)d_in[8];
  const float* w2   = (const float*)d_in[9];
  // d_in[10] relation_vectors: softmax-invariant constant -> unused.
  const float* attv = (const float*)d_in[11];
  const float* cw   = (const float*)d_in[12];
  float* out = (float*)d_out;

  char* p = (char*)d_ws;
  auto take = [&](size_t n) { char* r = p; p += (n + 255) & ~(size_t)255; return r; };
  unsigned char* wp   = (unsigned char*)take(24 * 16384);
  unsigned char* xgwp = (unsigned char*)take((size_t)Rc * 256 * 16384);   // 12.6 MB (reused as P|Q)
  float* xdw    = (float*)take((size_t)Rc * D1c * 128 * 4);
  float* aggP   = (float*)take((size_t)KH1 * Rc * D1c * 128 * 4);         // 25.2 MB (reused as aggP2)
  float* h1     = (float*)take((size_t)Rc * D1c * 128 * 4);
  float* score1 = (float*)take((size_t)Rc * D1c * 4);
  unsigned char* PGp = (unsigned char*)take((size_t)Rc * 64 * 16384);
  float* h2     = (float*)take((size_t)Rc * D2c * 128 * 4);
  float* score2 = (float*)take((size_t)Rc * D2c * 4);
  float* P = (float*)xgwp;                       // alias after gemm_big #1
  float* Q = P + (size_t)Rc * D1c * 128;
  float* aggP2 = aggP;                           // alias after combine1

  wpack<<<dim3(12, 2), 256, 0, stream>>>(w1, w2, wp);
  gg_layer1<<<dim3(320, Rc), 256, 0, stream>>>(feat, srcn, d2s1, d2d1, wp, xgwp, xdw);
  gemm_big<1><<<768, 256, 0, stream>>>(dif1, xgwp, aggP, D1c, S1c, KH1);
  combine1<<<dim3(D1c / 8, Rc), 128, 0, stream>>>(aggP, xdw, attv, h1, score1);
  k4_softmax1<<<Rc, 1024, 0, stream>>>(score1);
  gg_layer2<<<dim3(D1c / 64, Rc, 2), 256, 0, stream>>>(h1, score1, wp, P, Q);
  pgpack<<<dim3(S2c / 64, Rc), 256, 0, stream>>>(P, d2s2, PGp);
  gemm_big<0><<<dim3(D2c / 64, KH2, Rc), 256, 0, stream>>>(dif2, PGp, aggP2, D2c, S2c, KH2);
  combine2<<<dim3(D2c / 8, Rc), 128, 0, stream>>>(aggP2, Q, d2d2, attv, h2, score2);
  k8_softmax2<<<Rc, 512, 0, stream>>>(score2);
  k9_final<<<D2c, 128, 0, stream>>>(h2, score2, cw, out);
}

// Round 5
// 284.891 us; speedup vs baseline: 2.2233x; 1.0004x over previous
//
#include <hip/hip_runtime.h>
#include <hip/hip_bf16.h>
#include <math.h>

constexpr int Rc  = 3;
constexpr int Fc  = 256;
constexpr int Hc  = 128;
constexpr int N0c = 16384;
constexpr int S1c = 16384;
constexpr int D1c = 4096;
constexpr int S2c = 4096;
constexpr int D2c = 512;
constexpr int KH1 = 4;    // K-split GEMM1 (hard-coded in swizzle decode)
constexpr int KH2 = 16;   // K-split GEMM2

typedef __bf16 bf16x8 __attribute__((ext_vector_type(8)));
typedef float  f32x4  __attribute__((ext_vector_type(4)));

__device__ __forceinline__ void glds16(const void* g, void* l) {
  __builtin_amdgcn_global_load_lds(
      (const __attribute__((address_space(1))) void*)g,
      (__attribute__((address_space(3))) void*)l, 16, 0, 0);
}

__device__ __forceinline__ bf16x8 cvt2(const float4 a, const float4 b) {
  bf16x8 c;
  c[0] = (__bf16)a.x; c[1] = (__bf16)a.y; c[2] = (__bf16)a.z; c[3] = (__bf16)a.w;
  c[4] = (__bf16)b.x; c[5] = (__bf16)b.y; c[6] = (__bf16)b.z; c[7] = (__bf16)b.w;
  return c;
}

__device__ __forceinline__ unsigned short bfbits(float v) {
  __bf16 b = (__bf16)v; unsigned short u;
  __builtin_memcpy(&u, &b, 2); return u;
}

// ---------------------------------------------------------------------------
// wpack: fp32 weight [rows x 128] -> packed bf16 hi/lo B-panels in GEMM-LDS
// image. 12 tiles: 0-3 w1top, 4-7 w1bot, 8-9 w2P, 10-11 w2Q. half=1 is the
// bf16 residual (v - bf16(v)). Block (0,0) also zeroes the esum accumulators.
// ---------------------------------------------------------------------------
__global__ __launch_bounds__(256, 2)
void wpack(const float* __restrict__ w1, const float* __restrict__ w2,
           unsigned char* __restrict__ wp, float* __restrict__ esum) {
  const int tile = blockIdx.x, half = blockIdx.y, t = threadIdx.x;
  if (tile == 0 && half == 0 && t < 8) esum[t] = 0.f;
  const float* src; int row0;
  if (tile < 4)       { src = w1; row0 = tile * 64; }
  else if (tile < 8)  { src = w1; row0 = 256 + (tile - 4) * 64; }
  else if (tile < 10) { src = w2; row0 = (tile - 8) * 64; }
  else                { src = w2; row0 = 128 + (tile - 10) * 64; }
  unsigned char* dst = wp + ((size_t)half * 12 + tile) * 16384;
  __shared__ float sm[64][132];
  {
    const int r = t >> 2, c0 = (t & 3) * 32;
#pragma unroll
    for (int j = 0; j < 8; j++)
      *(float4*)&sm[r][c0 + 4 * j] = *(const float4*)(src + (size_t)(row0 + r) * 128 + c0 + 4 * j);
  }
  __syncthreads();
  if (t < 128) {
    const int n = t;
#pragma unroll
    for (int ch = 0; ch < 8; ch++) {
      bf16x8 o;
#pragma unroll
      for (int e = 0; e < 8; e++) {
        float v = sm[ch * 8 + e][n];
        __bf16 h = (__bf16)v;
        o[e] = half ? (__bf16)(v - (float)h) : h;
      }
      *(bf16x8*)(dst + n * 128 + ((ch ^ (n & 7)) * 16)) = o;
    }
  }
}

// ---------------------------------------------------------------------------
// gg_layer1: fused layer-1 projections (two jobs, split by blockIdx.x):
//   job0 (bx<256):  xgw = gather(feat; srcn.d2s1) @ (w1t_h+w1t_l) -> packed panel
//   job1 (bx>=256): xdw = gather(feat; srcn.d2d1) @ (w1b_h+w1b_l) -> fp32
// All 16 A-loads (full K=256 slice) issued upfront: gather HBM latency paid
// once per block, hidden under the B staging + compute of early tiles.
// ---------------------------------------------------------------------------
__global__ __launch_bounds__(256, 3)
void gg_layer1(const float* __restrict__ feat, const int* __restrict__ srcn,
               const int* __restrict__ d2s1, const int* __restrict__ d2d1,
               const unsigned char* __restrict__ wp,
               unsigned char* __restrict__ xgwp, float* __restrict__ xdw) {
  const int rel = blockIdx.y;
  int bx = blockIdx.x;
  const int job = bx >= 256 ? 1 : 0;
  if (job) bx -= 256;
  const int s0 = bx * 64;
  const int rows = job ? D1c : S1c;
  const int* idx = job ? d2d1 : d2s1;
  const unsigned char* Bh = wp + (size_t)(job ? 4 : 0) * 16384;
  const unsigned char* Bl = wp + (size_t)(12 + (job ? 4 : 0)) * 16384;

  const int t = threadIdx.x, lane = t & 63, w = t >> 6;
  const int mh = w >> 1, nh = w & 1;

  __shared__ __bf16 Asm[64 * 64];
  __shared__ __bf16 Bhs[128 * 64];
  __shared__ __bf16 Bls[128 * 64];

  const int arow = t >> 2, ak0 = (t & 3) * 16;
  const int row = s0 + arow;
  const size_t arowg = (size_t)srcn[rel * N0c + idx[(size_t)rel * rows + row]];
  const float* aptr = feat + arowg * Fc + ak0;
  const int ac0 = ak0 >> 3;
  __bf16* asw0 = &Asm[arow * 64 + ((ac0    ) ^ (arow & 7)) * 8];
  __bf16* asw1 = &Asm[arow * 64 + ((ac0 + 1) ^ (arow & 7)) * 8];

  // whole K=256 row-slice upfront (16 x dwordx4)
  float4 a[16];
#pragma unroll
  for (int tl = 0; tl < 4; tl++)
#pragma unroll
    for (int j = 0; j < 4; j++) a[tl * 4 + j] = *(const float4*)(aptr + tl * 64 + 4 * j);

  f32x4 acc[2][4] = {};

  for (int tl = 0; tl < 4; ++tl) {
    asm volatile("s_waitcnt lgkmcnt(0)" ::: "memory");
    __builtin_amdgcn_s_barrier();
    __builtin_amdgcn_sched_barrier(0);
    {
      const unsigned char* bh = Bh + (size_t)tl * 16384 + w * 4096 + lane * 16;
      const unsigned char* bl = Bl + (size_t)tl * 16384 + w * 4096 + lane * 16;
      char* dh = (char*)Bhs + w * 4096;
      char* dl = (char*)Bls + w * 4096;
#pragma unroll
      for (int i = 0; i < 4; i++) glds16(bh + i * 1024, dh + i * 1024);
#pragma unroll
      for (int i = 0; i < 4; i++) glds16(bl + i * 1024, dl + i * 1024);
    }
    *(bf16x8*)asw0 = cvt2(a[tl * 4 + 0], a[tl * 4 + 1]);
    *(bf16x8*)asw1 = cvt2(a[tl * 4 + 2], a[tl * 4 + 3]);
    asm volatile("s_waitcnt vmcnt(0) lgkmcnt(0)" ::: "memory");
    __builtin_amdgcn_s_barrier();
    __builtin_amdgcn_sched_barrier(0);
#pragma unroll
    for (int ks = 0; ks < 2; ks++) {
      const int ch = ks * 4 + (lane >> 4);
      bf16x8 af[2], bh[4], bl[4];
#pragma unroll
      for (int mi = 0; mi < 2; mi++) {
        int r = mh * 32 + mi * 16 + (lane & 15);
        af[mi] = *(const bf16x8*)&Asm[r * 64 + ((ch ^ (r & 7)) * 8)];
      }
#pragma unroll
      for (int ni = 0; ni < 4; ni++) {
        int n = nh * 64 + ni * 16 + (lane & 15);
        bh[ni] = *(const bf16x8*)&Bhs[n * 64 + ((ch ^ (n & 7)) * 8)];
        bl[ni] = *(const bf16x8*)&Bls[n * 64 + ((ch ^ (n & 7)) * 8)];
      }
#pragma unroll
      for (int mi = 0; mi < 2; mi++)
#pragma unroll
        for (int ni = 0; ni < 4; ni++) {
          acc[mi][ni] = __builtin_amdgcn_mfma_f32_16x16x32_bf16(af[mi], bh[ni], acc[mi][ni], 0, 0, 0);
          acc[mi][ni] = __builtin_amdgcn_mfma_f32_16x16x32_bf16(af[mi], bl[ni], acc[mi][ni], 0, 0, 0);
        }
    }
  }
  if (job) {
#pragma unroll
    for (int mi = 0; mi < 2; mi++)
#pragma unroll
      for (int ni = 0; ni < 4; ni++) {
        const int col = nh * 64 + ni * 16 + (lane & 15);
#pragma unroll
        for (int j = 0; j < 4; j++) {
          const int r = mh * 32 + mi * 16 + (lane >> 4) * 4 + j;
          xdw[((size_t)rel * D1c + s0 + r) * 128 + col] = acc[mi][ni][j];
        }
      }
  } else {
    unsigned char* tile = xgwp + ((size_t)(rel * (S1c >> 6) + bx)) * 16384;
#pragma unroll
    for (int mi = 0; mi < 2; mi++)
#pragma unroll
      for (int ni = 0; ni < 4; ni++) {
        const int sl0 = mh * 32 + mi * 16 + (lane >> 4) * 4;
        const int n = nh * 64 + ni * 16 + (lane & 15);
        const int ch = sl0 >> 3, e0 = sl0 & 7, cs = ch ^ (n & 7);
        ushort4 u;
        u.x = bfbits(acc[mi][ni][0]); u.y = bfbits(acc[mi][ni][1]);
        u.z = bfbits(acc[mi][ni][2]); u.w = bfbits(acc[mi][ni][3]);
        *(ushort4*)(tile + n * 128 + cs * 16 + e0 * 2) = u;
      }
  }
}

// ---------------------------------------------------------------------------
// gemm_big: C_partial[kh] = A[rel][m][k-slice] @ Bpanel   (N=128, BK=64)
//   SWZ=1: XCD-locality swizzle for the 768-block dif1 GEMM (KH1=4).
// ---------------------------------------------------------------------------
template <int SWZ>
__global__ __launch_bounds__(256, 3)
void gemm_big(const float* __restrict__ A, const unsigned char* __restrict__ Bp,
              float* __restrict__ C, int M, int KTOT, int KH) {
  int rel, kh, m0;
  if (SWZ) {
    const int F = blockIdx.x;            // 768 blocks
    const int xcd = F & 7, r = F >> 3;   // r in [0,96)
    const int sub = r >> 5, m = r & 31;  // sub in [0,3)
    const int h = xcd + 8 * sub;         // half-group [0,24)
    const int g = h >> 1;                // group [0,12) = rel*4+kh
    rel = g >> 2; kh = g & 3;
    m0 = ((h & 1) * 32 + m) * 64;
  } else {
    rel = blockIdx.z; kh = blockIdx.y; m0 = blockIdx.x * 64;
  }
  const int t = threadIdx.x, lane = t & 63, w = t >> 6;
  const int KB = KTOT / KH, NT = KB >> 6;
  const int mh = w >> 1, nh = w & 1;

  const float* Ag = A + ((size_t)rel * M + m0) * KTOT + (size_t)kh * KB;
  const unsigned char* Bt = Bp + ((size_t)rel * (KTOT >> 6) + (size_t)kh * NT) * 16384;
  float* Cg = C + (((size_t)kh * Rc + rel) * M + m0) * 128;

  __shared__ __bf16 Asm[64 * 64];        // 8 KB
  __shared__ __bf16 Bsm[2][128 * 64];    // 2 x 16 KB

  f32x4 acc[2][4] = {};
  const int arow = t >> 2, ak0 = (t & 3) * 16;
  const float* aptr = Ag + (size_t)arow * KTOT + ak0;
  const int ac0 = ak0 >> 3;
  __bf16* asw0 = &Asm[arow * 64 + ((ac0    ) ^ (arow & 7)) * 8];
  __bf16* asw1 = &Asm[arow * 64 + ((ac0 + 1) ^ (arow & 7)) * 8];
  const unsigned char* bsrc = Bt + w * 4096 + lane * 16;

  float4 a0[4], a1[4];
#pragma unroll
  for (int j = 0; j < 4; j++) a0[j] = *(const float4*)(aptr + 4 * j);
  {
    char* bd = (char*)Bsm[0] + w * 4096;
#pragma unroll
    for (int i = 0; i < 4; i++) glds16(bsrc + i * 1024, bd + i * 1024);
  }

  for (int tl = 0; tl < NT; ++tl) {
    const int cur = tl & 1;
    asm volatile("s_waitcnt lgkmcnt(0)" ::: "memory");
    __builtin_amdgcn_s_barrier();
    __builtin_amdgcn_sched_barrier(0);
    if (tl + 1 < NT) {
      const unsigned char* bs = bsrc + (size_t)(tl + 1) * 16384;
      char* bd = (char*)Bsm[cur ^ 1] + w * 4096;
#pragma unroll
      for (int i = 0; i < 4; i++) glds16(bs + i * 1024, bd + i * 1024);
      const float* ap = aptr + (size_t)(tl + 1) * 64;
#pragma unroll
      for (int j = 0; j < 4; j++) a1[j] = *(const float4*)(ap + 4 * j);
    }
    *(bf16x8*)asw0 = cvt2(a0[0], a0[1]);
    *(bf16x8*)asw1 = cvt2(a0[2], a0[3]);
    if (tl + 1 < NT)
      asm volatile("s_waitcnt vmcnt(8) lgkmcnt(0)" ::: "memory");
    else
      asm volatile("s_waitcnt vmcnt(0) lgkmcnt(0)" ::: "memory");
    __builtin_amdgcn_s_barrier();
    __builtin_amdgcn_sched_barrier(0);
    const __bf16* Bc = Bsm[cur];
#pragma unroll
    for (int ks = 0; ks < 2; ks++) {
      const int ch = ks * 4 + (lane >> 4);
      bf16x8 af[2], bfr[4];
#pragma unroll
      for (int mi = 0; mi < 2; mi++) {
        int r = mh * 32 + mi * 16 + (lane & 15);
        af[mi] = *(const bf16x8*)&Asm[r * 64 + ((ch ^ (r & 7)) * 8)];
      }
#pragma unroll
      for (int ni = 0; ni < 4; ni++) {
        int n = nh * 64 + ni * 16 + (lane & 15);
        bfr[ni] = *(const bf16x8*)&Bc[n * 64 + ((ch ^ (n & 7)) * 8)];
      }
#pragma unroll
      for (int mi = 0; mi < 2; mi++)
#pragma unroll
        for (int ni = 0; ni < 4; ni++)
          acc[mi][ni] = __builtin_amdgcn_mfma_f32_16x16x32_bf16(af[mi], bfr[ni], acc[mi][ni], 0, 0, 0);
    }
#pragma unroll
    for (int j = 0; j < 4; j++) a0[j] = a1[j];
  }
#pragma unroll
  for (int mi = 0; mi < 2; mi++)
#pragma unroll
    for (int ni = 0; ni < 4; ni++) {
      const int col = nh * 64 + ni * 16 + (lane & 15);
#pragma unroll
      for (int j = 0; j < 4; j++) {
        const int r = mh * 32 + mi * 16 + (lane >> 4) * 4 + j;
        Cg[(size_t)r * 128 + col] = acc[mi][ni][j];
      }
    }
}

// ---------------------------------------------------------------------------
// c1_l2: FUSED combine1 + layer-2 projections.
//   h = sum_kh aggP + xdw   (64 rows x 128, kept in regs/LDS; never stored)
//   e = exp(h . attv); escore1 <- e; esum[rel] += block-sum(e)
//   P' = h @ w2top, Q' = h @ w2bot   (att-scale deferred to consumers)
// ---------------------------------------------------------------------------
__global__ __launch_bounds__(256, 3)
void c1_l2(const float* __restrict__ aggP, const float* __restrict__ xdw,
           const float* __restrict__ attv, const unsigned char* __restrict__ wp,
           float* __restrict__ escore1, float* __restrict__ esum,
           float* __restrict__ P, float* __restrict__ Q) {
  const int rel = blockIdx.y, d0 = blockIdx.x * 64;
  const int t = threadIdx.x, lane = t & 63, w = t >> 6;
  const int mh = w >> 1, nh = w & 1;

  __shared__ __bf16 Asm[64 * 128];   // 16 KB, K=128 swizzled (16 chunks/row)
  __shared__ __bf16 Bhs[128 * 64];   // 16 KB
  __shared__ __bf16 Bls[128 * 64];   // 16 KB
  __shared__ float  sred[64];

  // ---- build h: thread t owns row r = t>>2, cols c0..c0+31 ----
  const int r = t >> 2, c0 = (t & 3) * 32;
  float4 x0[8];
  {
    const size_t base = ((size_t)rel * D1c + d0 + r) * 128 + c0;
#pragma unroll
    for (int j = 0; j < 8; j++) x0[j] = *(const float4*)(xdw + base + 4 * j);
#pragma unroll
    for (int p2 = 0; p2 < KH1; p2++) {
      const float* ap = aggP + (((size_t)p2 * Rc + rel) * D1c + d0 + r) * 128 + c0;
#pragma unroll
      for (int j = 0; j < 8; j++) {
        float4 u = *(const float4*)(ap + 4 * j);
        x0[j].x += u.x; x0[j].y += u.y; x0[j].z += u.z; x0[j].w += u.w;
      }
    }
  }
  // ---- score partial + row-reduce over the 4 threads of the row ----
  float sp = 0.f;
#pragma unroll
  for (int j = 0; j < 8; j++) {
    sp += x0[j].x * attv[c0 + 4 * j]     + x0[j].y * attv[c0 + 4 * j + 1]
        + x0[j].z * attv[c0 + 4 * j + 2] + x0[j].w * attv[c0 + 4 * j + 3];
  }
  sp += __shfl_xor(sp, 1); sp += __shfl_xor(sp, 2);
  const float e = expf(sp);
  if ((t & 3) == 0) { escore1[(size_t)rel * D1c + d0 + r] = e; sred[r] = e; }
  // ---- write h as bf16 swizzled A panel (chunk idx 0..15 per row) ----
  const int ch0 = (t & 3) * 4;
#pragma unroll
  for (int q = 0; q < 4; q++) {
    *(bf16x8*)&Asm[r * 128 + (((ch0 + q) ^ (r & 7)) * 8)] = cvt2(x0[2 * q], x0[2 * q + 1]);
  }
  __syncthreads();
  if (t < 64) {
    float v = sred[t];
    v += __shfl_down(v, 32); v += __shfl_down(v, 16); v += __shfl_down(v, 8);
    v += __shfl_down(v, 4);  v += __shfl_down(v, 2);  v += __shfl_down(v, 1);
    if (t == 0) atomicAdd(esum + rel, v);
  }
  // ---- two GEMMs: z=0 -> P (wp tiles 8,9 hi / 20,21 lo), z=1 -> Q (10,11/22,23)
  f32x4 accP[2][4] = {}, accQ[2][4] = {};
#pragma unroll
  for (int z = 0; z < 2; z++) {
#pragma unroll
    for (int tl = 0; tl < 2; tl++) {
      if (!(z == 0 && tl == 0)) {
        asm volatile("s_waitcnt lgkmcnt(0)" ::: "memory");
        __builtin_amdgcn_s_barrier();
        __builtin_amdgcn_sched_barrier(0);
      }
      {
        const unsigned char* bh = wp + (size_t)(8 + z * 2 + tl) * 16384 + w * 4096 + lane * 16;
        const unsigned char* bl = wp + (size_t)(20 + z * 2 + tl) * 16384 + w * 4096 + lane * 16;
        char* dh = (char*)Bhs + w * 4096;
        char* dl = (char*)Bls + w * 4096;
#pragma unroll
        for (int i = 0; i < 4; i++) glds16(bh + i * 1024, dh + i * 1024);
#pragma unroll
        for (int i = 0; i < 4; i++) glds16(bl + i * 1024, dl + i * 1024);
      }
      asm volatile("s_waitcnt vmcnt(0) lgkmcnt(0)" ::: "memory");
      __builtin_amdgcn_s_barrier();
      __builtin_amdgcn_sched_barrier(0);
      f32x4 (*acc)[4] = z ? accQ : accP;
#pragma unroll
      for (int ks = 0; ks < 2; ks++) {
        const int lch = ks * 4 + (lane >> 4);      // chunk within the staged tile
        const int ch  = tl * 8 + lch;              // chunk within Asm row
        bf16x8 af[2], bh[4], bl[4];
#pragma unroll
        for (int mi = 0; mi < 2; mi++) {
          int rr = mh * 32 + mi * 16 + (lane & 15);
          af[mi] = *(const bf16x8*)&Asm[rr * 128 + ((ch ^ (rr & 7)) * 8)];
        }
#pragma unroll
        for (int ni = 0; ni < 4; ni++) {
          int n = nh * 64 + ni * 16 + (lane & 15);
          bh[ni] = *(const bf16x8*)&Bhs[n * 64 + ((lch ^ (n & 7)) * 8)];
          bl[ni] = *(const bf16x8*)&Bls[n * 64 + ((lch ^ (n & 7)) * 8)];
        }
#pragma unroll
        for (int mi = 0; mi < 2; mi++)
#pragma unroll
          for (int ni = 0; ni < 4; ni++) {
            acc[mi][ni] = __builtin_amdgcn_mfma_f32_16x16x32_bf16(af[mi], bh[ni], acc[mi][ni], 0, 0, 0);
            acc[mi][ni] = __builtin_amdgcn_mfma_f32_16x16x32_bf16(af[mi], bl[ni], acc[mi][ni], 0, 0, 0);
          }
      }
    }
  }
  // ---- epilogue ----
#pragma unroll
  for (int mi = 0; mi < 2; mi++)
#pragma unroll
    for (int ni = 0; ni < 4; ni++) {
      const int col = nh * 64 + ni * 16 + (lane & 15);
#pragma unroll
      for (int j = 0; j < 4; j++) {
        const int rr = mh * 32 + mi * 16 + (lane >> 4) * 4 + j;
        P[((size_t)rel * D1c + d0 + rr) * 128 + col] = accP[mi][ni][j];
        Q[((size_t)rel * D1c + d0 + rr) * 128 + col] = accQ[mi][ni][j];
      }
    }
}

// ---------------------------------------------------------------------------
// pgpack: PG panel (GEMM2 B) <- gather P rows via d2s2, scale by att1, bf16,
//         packed/swizzled.  att1[row] = escore1[row] / esum[rel].
// ---------------------------------------------------------------------------
__global__ __launch_bounds__(256, 2)
void pgpack(const float* __restrict__ P, const int* __restrict__ d2s2,
            const float* __restrict__ escore1, const float* __restrict__ esum,
            unsigned char* __restrict__ PGp) {
  const int rel = blockIdx.y, kb = blockIdx.x, t = threadIdx.x;
  const float inv1 = 1.0f / esum[rel];
  __shared__ __bf16 sm[64][136];
  {
    const int kl = t >> 2, c0 = (t & 3) * 32;
    const int sr = d2s2[rel * S2c + kb * 64 + kl];
    const float sc = escore1[(size_t)rel * D1c + sr] * inv1;
    const float4* p = (const float4*)(P + ((size_t)rel * D1c + sr) * 128 + c0);
#pragma unroll
    for (int j = 0; j < 4; j++) {
      float4 v0 = p[2 * j], v1 = p[2 * j + 1];
      v0.x *= sc; v0.y *= sc; v0.z *= sc; v0.w *= sc;
      v1.x *= sc; v1.y *= sc; v1.z *= sc; v1.w *= sc;
      *(bf16x8*)&sm[kl][c0 + 8 * j] = cvt2(v0, v1);
    }
  }
  __syncthreads();
  if (t < 128) {
    const int n = t;
    unsigned char* dst = PGp + ((size_t)(rel * (S2c >> 6) + kb)) * 16384;
#pragma unroll
    for (int ch = 0; ch < 8; ch++) {
      bf16x8 o;
#pragma unroll
      for (int e = 0; e < 8; e++) o[e] = sm[ch * 8 + e][n];
      *(bf16x8*)(dst + n * 128 + ((ch ^ (n & 7)) * 16)) = o;
    }
  }
}

// ---------------------------------------------------------------------------
// combine2: h2 = sum_kh2 aggP2 + att1[qr]*Q[qr] ; e2 = exp(h2 . attv);
//           escore2 <- e2 ; esum[4+rel] += block-sum(e2)
// ---------------------------------------------------------------------------
__global__ __launch_bounds__(128, 4)
void combine2(const float* __restrict__ aggP2, const float* __restrict__ Q,
              const int* __restrict__ d2d2, const float* __restrict__ attv,
              const float* __restrict__ escore1, const float* __restrict__ esum,
              float* __restrict__ h2, float* __restrict__ escore2) {
  const int rel = blockIdx.y, d0 = blockIdx.x * 8, t = threadIdx.x;
  const float inv1 = 1.0f / esum[rel];
  float acc[8];
#pragma unroll
  for (int i = 0; i < 8; i++) {
    const int d = d0 + i;
    const int qr = d2d2[rel * D2c + d];
    const float qs = escore1[(size_t)rel * D1c + qr] * inv1;
    float v = Q[((size_t)rel * D1c + qr) * 128 + t] * qs;
#pragma unroll
    for (int p = 0; p < KH2; p++)
      v += aggP2[(((size_t)p * Rc + rel) * D2c + d) * 128 + t];
    acc[i] = v;
    h2[((size_t)rel * D2c + d) * 128 + t] = v;
  }
  const float avt = attv[t];
  __shared__ float sred[2][8];
#pragma unroll
  for (int i = 0; i < 8; i++) {
    float p = acc[i] * avt;
    p += __shfl_down(p, 32); p += __shfl_down(p, 16); p += __shfl_down(p, 8);
    p += __shfl_down(p, 4);  p += __shfl_down(p, 2);  p += __shfl_down(p, 1);
    if ((t & 63) == 0) sred[t >> 6][i] = p;
  }
  __syncthreads();
  if (t < 8) {
    const float e2 = expf(sred[0][t] + sred[1][t]);
    escore2[rel * D2c + d0 + t] = e2;
    float v = e2;
    v += __shfl_down(v, 4); v += __shfl_down(v, 2); v += __shfl_down(v, 1);
    if (t == 0) atomicAdd((float*)esum + 4 + rel, v);
  }
}

// ---------------------------------------------------------------------------
// k9: summed = sum_r h2 * att2 ; l2-normalize; logits = normed@cw; softmax
// ---------------------------------------------------------------------------
__global__ __launch_bounds__(128, 4)
void k9_final(const float* __restrict__ h2, const float* __restrict__ escore2,
              const float* __restrict__ esum, const float* __restrict__ cw,
              float* __restrict__ out) {
  const int d = blockIdx.x, t = threadIdx.x;
  float v = 0.f;
#pragma unroll
  for (int r = 0; r < Rc; r++) {
    const float att = escore2[r * D2c + d] / esum[4 + r];
    v += h2[((size_t)r * D2c + d) * Hc + t] * att;
  }
  float ss = v * v;
  ss += __shfl_down(ss, 32); ss += __shfl_down(ss, 16); ss += __shfl_down(ss, 8);
  ss += __shfl_down(ss, 4);  ss += __shfl_down(ss, 2);  ss += __shfl_down(ss, 1);
  __shared__ float sr[3][2];
  if ((t & 63) == 0) sr[0][t >> 6] = ss;
  __syncthreads();
  const float tot = sr[0][0] + sr[0][1];
  const float inv = rsqrtf(fmaxf(tot, 1e-12f));
  const float nv = v * inv;
  float p0 = nv * cw[t * 2], p1 = nv * cw[t * 2 + 1];
  p0 += __shfl_down(p0, 32); p0 += __shfl_down(p0, 16); p0 += __shfl_down(p0, 8);
  p0 += __shfl_down(p0, 4);  p0 += __shfl_down(p0, 2);  p0 += __shfl_down(p0, 1);
  p1 += __shfl_down(p1, 32); p1 += __shfl_down(p1, 16); p1 += __shfl_down(p1, 8);
  p1 += __shfl_down(p1, 4);  p1 += __shfl_down(p1, 2);  p1 += __shfl_down(p1, 1);
  if ((t & 63) == 0) { sr[1][t >> 6] = p0; sr[2][t >> 6] = p1; }
  __syncthreads();
  if (t == 0) {
    const float l0 = sr[1][0] + sr[1][1];
    const float l1 = sr[2][0] + sr[2][1];
    const float m = fmaxf(l0, l1);
    const float e0 = expf(l0 - m), e1 = expf(l1 - m);
    const float is = 1.0f / (e0 + e1);
    out[d * 2 + 0] = e0 * is;
    out[d * 2 + 1] = e1 * is;
  }
}

// ---------------------------------------------------------------------------
extern "C" void kernel_launch(void* const* d_in, const int* in_sizes, int n_in,
                              void* d_out, int out_size, void* d_ws, size_t ws_size,
                              hipStream_t stream) {
  (void)in_sizes; (void)n_in; (void)out_size; (void)ws_size;
  const float* feat = (const float*)d_in[0];
  const int*   srcn = (const int*)d_in[1];
  const int*   d2s1 = (const int*)d_in[2];
  const int*   d2d1 = (const int*)d_in[3];
  const float* dif1 = (const float*)d_in[4];
  const int*   d2s2 = (const int*)d_in[5];
  const int*   d2d2 = (const int*)d_in[6];
  const float* dif2 = (const float*)d_in[7];
  const float* w1   = (const float*)d_in[8];
  const float* w2   = (const float*)d_in[9];
  // d_in[10] relation_vectors: softmax-invariant constant -> unused.
  const float* attv = (const float*)d_in[11];
  const float* cw   = (const float*)d_in[12];
  float* out = (float*)d_out;

  char* p = (char*)d_ws;
  auto take = [&](size_t n) { char* r = p; p += (n + 255) & ~(size_t)255; return r; };
  unsigned char* wp   = (unsigned char*)take(24 * 16384);
  unsigned char* xgwp = (unsigned char*)take((size_t)Rc * 256 * 16384);   // 12.6 MB (reused as P|Q)
  float* xdw    = (float*)take((size_t)Rc * D1c * 128 * 4);
  float* aggP   = (float*)take((size_t)KH1 * Rc * D1c * 128 * 4);         // 25.2 MB (reused as aggP2)
  float* escore1= (float*)take((size_t)Rc * D1c * 4);
  float* esum   = (float*)take(256);
  unsigned char* PGp = (unsigned char*)take((size_t)Rc * 64 * 16384);
  float* h2     = (float*)take((size_t)Rc * D2c * 128 * 4);
  float* escore2= (float*)take((size_t)Rc * D2c * 4);
  float* P = (float*)xgwp;                       // alias after gemm_big #1
  float* Q = P + (size_t)Rc * D1c * 128;
  float* aggP2 = aggP;                           // alias after c1_l2

  wpack<<<dim3(12, 2), 256, 0, stream>>>(w1, w2, wp, esum);
  gg_layer1<<<dim3(320, Rc), 256, 0, stream>>>(feat, srcn, d2s1, d2d1, wp, xgwp, xdw);
  gemm_big<1><<<768, 256, 0, stream>>>(dif1, xgwp, aggP, D1c, S1c, KH1);
  c1_l2<<<dim3(D1c / 64, Rc), 256, 0, stream>>>(aggP, xdw, attv, wp, escore1, esum, P, Q);
  pgpack<<<dim3(S2c / 64, Rc), 256, 0, stream>>>(P, d2s2, escore1, esum, PGp);
  gemm_big<0><<<dim3(D2c / 64, KH2, Rc), 256, 0, stream>>>(dif2, PGp, aggP2, D2c, S2c, KH2);
  combine2<<<dim3(D2c / 8, Rc), 128, 0, stream>>>(aggP2, Q, d2d2, attv, escore1, esum, h2, escore2);
  k9_final<<<D2c, 128, 0, stream>>>(h2, escore2, esum, cw, out);
}